// Round 2
// 615.269 us; speedup vs baseline: 1.0620x; 1.0620x over previous
//
#include <hip/hip_runtime.h>
#include <hip/hip_bf16.h>

using bf16 = __hip_bfloat16;

#define LQ      1024
#define NBAT    2
#define DMOD    1024
#define NHEAD   16
#define DHEAD   64
#define DFFN    4096
#define MEMLEN  1024
#define TKEY    2048
#define HDIM    1024
#define SCALE_F 0.125f
#define EPS_F   1e-5f

typedef __attribute__((ext_vector_type(8))) short short8;
typedef __attribute__((ext_vector_type(4))) float f32x4;

__device__ __forceinline__ float ldf(const float* p) { return *p; }
__device__ __forceinline__ float ldf(const bf16* p) { return __bfloat162float(*p); }
__device__ __forceinline__ void stf(float* p, float v) { *p = v; }
__device__ __forceinline__ void stf(bf16* p, float v) { *p = __float2bfloat16(v); }

// copy 4 elements (converting to bf16) into LDS, 8B store
__device__ __forceinline__ void cpy4(bf16* dst, const float* src) {
    float4 w = *(const float4*)src;
    bf16 t[4] = {__float2bfloat16(w.x), __float2bfloat16(w.y),
                 __float2bfloat16(w.z), __float2bfloat16(w.w)};
    *(uint2*)dst = *(uint2*)t;
}
__device__ __forceinline__ void cpy4(bf16* dst, const bf16* src) {
    *(uint2*)dst = *(const uint2*)src;
}

// async global->LDS 16B: LDS dest is wave-uniform base + lane*16
__device__ __forceinline__ void gload_lds16(const bf16* g, bf16* l) {
    __builtin_amdgcn_global_load_lds(
        (const __attribute__((address_space(1))) unsigned int*)g,
        (__attribute__((address_space(3))) unsigned int*)l, 16, 0, 0);
}

// ---------------- fp32 -> bf16 elementwise convert (8 elems/thread) ----------------
__global__ __launch_bounds__(256)
void cvt_bf16_k(const float* __restrict__ in, bf16* __restrict__ out, int n)
{
    const int i = (blockIdx.x * 256 + threadIdx.x) * 8;
    if (i >= n) return;
    float4 v0 = *(const float4*)(in + i);
    float4 v1 = *(const float4*)(in + i + 4);
    bf16 t[8] = {__float2bfloat16(v0.x), __float2bfloat16(v0.y),
                 __float2bfloat16(v0.z), __float2bfloat16(v0.w),
                 __float2bfloat16(v1.x), __float2bfloat16(v1.y),
                 __float2bfloat16(v1.z), __float2bfloat16(v1.w)};
    *(uint4*)(out + i) = *(uint4*)t;
}

// ---------------- W [K][N] fp32 -> Wt [N][K] bf16 (64x64 tiles) ----------------
__global__ __launch_bounds__(256)
void tcvt_bf16_k(const float* __restrict__ W, bf16* __restrict__ Wt, int K, int N)
{
    __shared__ alignas(16) bf16 tile[64][65];
    const int n0 = blockIdx.x * 64, k0 = blockIdx.y * 64;
    const int tid = threadIdx.x;
    const int r = tid >> 2, cb = (tid & 3) * 16;
    #pragma unroll
    for (int e = 0; e < 16; e++)
        tile[r][cb + e] = __float2bfloat16(W[(size_t)(k0 + r) * N + n0 + cb + e]);
    __syncthreads();
    bf16 t[16];
    #pragma unroll
    for (int e = 0; e < 16; e++) t[e] = tile[cb + e][r];
    bf16* dst = Wt + (size_t)(n0 + r) * K + k0 + cb;
    *(uint4*)dst       = ((uint4*)t)[0];
    *(uint4*)(dst + 8) = ((uint4*)t)[1];
}

// ---------------- MFMA GEMM, 128x128 tile, BK=64, global_load_lds (m97 structure) ----
// A [M][K] bf16 row-major, Bt [N][K] bf16 row-major (pre-transposed weights).
// 256 threads = 4 waves in 2x2; each wave computes a 64x64 output sub-tile.
// LDS 32 KB linear [row][64]; staged via global_load_lds width 16.
template<bool RELU, typename TOUT>
__global__ __launch_bounds__(256)
void mgemm128_k(const bf16* __restrict__ A, const bf16* __restrict__ Bt,
                const float* __restrict__ bias, TOUT* __restrict__ C,
                int M, int N, int K)
{
    __shared__ alignas(16) bf16 As[128 * 64];
    __shared__ alignas(16) bf16 Bs[128 * 64];
    const int tid  = threadIdx.x;
    const int wave = tid >> 6, lane = tid & 63;
    const int m0 = blockIdx.y * 128, n0 = blockIdx.x * 128;
    const int g = lane >> 4, c16 = lane & 15;
    const int wr = (wave >> 1) * 64, wc = (wave & 1) * 64;

    f32x4 acc[4][4];
    #pragma unroll
    for (int mi = 0; mi < 4; mi++)
        #pragma unroll
        for (int ni = 0; ni < 4; ni++) acc[mi][ni] = (f32x4)(0.f);

    // staging map: wave w issue q covers rows 32w + 8q + (lane>>3), k-cols (lane&7)*8
    const int r0 = (wave << 5) + (lane >> 3);
    const int cc = (lane & 7) << 3;
    const bf16* agp = A  + (size_t)(m0 + r0) * K + cc;
    const bf16* bgp = Bt + (size_t)(n0 + r0) * K + cc;
    bf16* al = &As[wave * 2048];
    bf16* bl = &Bs[wave * 2048];

    for (int k0 = 0; k0 < K; k0 += 64) {
        #pragma unroll
        for (int q = 0; q < 4; q++) {
            gload_lds16(agp + k0 + (size_t)(q * 8) * K, al + q * 512);
            gload_lds16(bgp + k0 + (size_t)(q * 8) * K, bl + q * 512);
        }
        __syncthreads();   // drains vmcnt before any wave reads LDS
        short8 af[4][2], bfr[4][2];
        #pragma unroll
        for (int mi = 0; mi < 4; mi++) {
            af[mi][0] = *(const short8*)&As[(wr + mi * 16 + c16) * 64 + g * 8];
            af[mi][1] = *(const short8*)&As[(wr + mi * 16 + c16) * 64 + 32 + g * 8];
        }
        #pragma unroll
        for (int ni = 0; ni < 4; ni++) {
            bfr[ni][0] = *(const short8*)&Bs[(wc + ni * 16 + c16) * 64 + g * 8];
            bfr[ni][1] = *(const short8*)&Bs[(wc + ni * 16 + c16) * 64 + 32 + g * 8];
        }
        #pragma unroll
        for (int mi = 0; mi < 4; mi++)
            #pragma unroll
            for (int ni = 0; ni < 4; ni++) {
                acc[mi][ni] = __builtin_amdgcn_mfma_f32_16x16x32_bf16(
                                  af[mi][0], bfr[ni][0], acc[mi][ni], 0, 0, 0);
                acc[mi][ni] = __builtin_amdgcn_mfma_f32_16x16x32_bf16(
                                  af[mi][1], bfr[ni][1], acc[mi][ni], 0, 0, 0);
            }
        __syncthreads();
    }

    // epilogue: C/D layout col=lane&15, row=(lane>>4)*4+reg
    const int crow = g * 4;
    #pragma unroll
    for (int ni = 0; ni < 4; ni++) {
        const int n = n0 + wc + ni * 16 + c16;
        const float bv = bias ? bias[n] : 0.f;
        #pragma unroll
        for (int mi = 0; mi < 4; mi++) {
            #pragma unroll
            for (int reg = 0; reg < 4; reg++) {
                const int m = m0 + wr + mi * 16 + crow + reg;
                float v = acc[mi][ni][reg] + bv;
                if (RELU) v = fmaxf(v, 0.f);
                stf(C + (size_t)m * N + n, v);
            }
        }
    }
}

// ---------------- MFMA GEMM, 64x64 tile (fallback path, fp32 weights) ----------------
template<typename TA, typename TOUT, bool RELU>
__global__ __launch_bounds__(256)
void mgemm64_k(const TA* __restrict__ A0, const TA* __restrict__ A1, int rowsplit,
               const float* __restrict__ Bw, const float* __restrict__ bias,
               TOUT* __restrict__ C, int M, int N, int K)
{
    __shared__ alignas(16) bf16 As[64][72];
    __shared__ alignas(16) bf16 Bs[64][72];
    const int tid  = threadIdx.x;
    const int m0   = blockIdx.y * 64;
    const int n0   = blockIdx.x * 64;
    const int wave = tid >> 6, lane = tid & 63;
    const int g = lane >> 4, c16 = lane & 15;

    f32x4 acc[4];
    #pragma unroll
    for (int nt = 0; nt < 4; nt++) acc[nt] = (f32x4)(0.f);

    const int ar = tid >> 2, akc = (tid & 3) * 16;
    const int grow = m0 + ar;
    const TA* Arow = (grow < rowsplit) ? (A0 + (size_t)grow * K)
                                       : (A1 + (size_t)(grow - rowsplit) * K);
    const int bn = tid & 63, bkb = (tid >> 6) * 16;
    const float* Bcol = Bw + n0 + bn;

    for (int k0 = 0; k0 < K; k0 += 64) {
        cpy4(&As[ar][akc],      Arow + k0 + akc);
        cpy4(&As[ar][akc + 4],  Arow + k0 + akc + 4);
        cpy4(&As[ar][akc + 8],  Arow + k0 + akc + 8);
        cpy4(&As[ar][akc + 12], Arow + k0 + akc + 12);
        {
            bf16 t16[16];
            #pragma unroll
            for (int e = 0; e < 16; e++)
                t16[e] = __float2bfloat16(Bcol[(size_t)(k0 + bkb + e) * N]);
            *(uint4*)&Bs[bn][bkb]     = *(uint4*)&t16[0];
            *(uint4*)&Bs[bn][bkb + 8] = *(uint4*)&t16[8];
        }
        __syncthreads();
        const short8 a0 = *(const short8*)&As[wave * 16 + c16][g * 8];
        const short8 a1 = *(const short8*)&As[wave * 16 + c16][32 + g * 8];
        #pragma unroll
        for (int nt = 0; nt < 4; nt++) {
            acc[nt] = __builtin_amdgcn_mfma_f32_16x16x32_bf16(
                          a0, *(const short8*)&Bs[nt * 16 + c16][g * 8], acc[nt], 0, 0, 0);
            acc[nt] = __builtin_amdgcn_mfma_f32_16x16x32_bf16(
                          a1, *(const short8*)&Bs[nt * 16 + c16][32 + g * 8], acc[nt], 0, 0, 0);
        }
        __syncthreads();
    }

    const int crow = (lane >> 4) * 4, ccol = lane & 15;
    #pragma unroll
    for (int nt = 0; nt < 4; nt++) {
        const int n = n0 + nt * 16 + ccol;
        const float bv = bias ? bias[n] : 0.f;
        #pragma unroll
        for (int rr = 0; rr < 4; rr++) {
            const int m = m0 + wave * 16 + crow + rr;
            float v = acc[nt][rr] + bv;
            if (RELU) v = fmaxf(v, 0.f);
            stf(C + (size_t)m * N + n, v);
        }
    }
}

union Frag8 { bf16 h[8]; short8 v; };

// ============ single-sweep online-softmax MFMA attention ============
// itile remap: grid is (x=16 i-tiles, y=32 bh), x-major dispatch pairs block n with
// n+256 on the same CU with the SAME i-tile (256%16==0) -> per-CU work 2*(17..32).
// Pair long with short instead: itile = (by<16) ? bx : 15-bx  -> constant 49/CU.
__global__ __launch_bounds__(256)
void flash_attn_k(const float* __restrict__ q, const bf16* __restrict__ kv,
                  const bf16* __restrict__ rg, const float* __restrict__ ub,
                  const float* __restrict__ vb,
                  float* __restrict__ m_arr, float* __restrict__ l_arr,
                  bf16* __restrict__ vec)
{
    __shared__ alignas(16) bf16 Ks[64][72];
    __shared__ alignas(16) bf16 Rs[128][72];
    __shared__ alignas(16) bf16 BDs[64][136];
    bf16 (*Vt)[72] = (bf16 (*)[72])&Rs[0][0];     // V^T [d][j], aliases Rs

    const int itile = (blockIdx.y < (NBAT * NHEAD / 2))
                          ? blockIdx.x : (gridDim.x - 1 - blockIdx.x);
    const int i0 = itile * 64;
    const int bh = blockIdx.y;
    const int b = bh >> 4, h = bh & 15;
    const int tid = threadIdx.x;
    const int wave = tid >> 6, lane = tid & 63;
    const int g = lane >> 4, c16 = lane & 15;
    const int dib = wave * 16 + g * 4;

    Frag8 fu0, fu1, fv0, fv1;
    {
        const float* qrow = q + ((size_t)(i0 + wave * 16 + c16) * NBAT + b) * HDIM + h * DHEAD;
        const float* ubp = ub + h * DHEAD;
        const float* vbp = vb + h * DHEAD;
        #pragma unroll
        for (int e = 0; e < 8; e++) {
            float q0 = qrow[g * 8 + e], q1 = qrow[32 + g * 8 + e];
            fu0.h[e] = __float2bfloat16(q0 + ubp[g * 8 + e]);
            fu1.h[e] = __float2bfloat16(q1 + ubp[32 + g * 8 + e]);
            fv0.h[e] = __float2bfloat16(q0 + vbp[g * 8 + e]);
            fv1.h[e] = __float2bfloat16(q1 + vbp[32 + g * 8 + e]);
        }
    }

    float mrow[4] = {-3e38f, -3e38f, -3e38f, -3e38f};
    float lrow[4] = {0.f, 0.f, 0.f, 0.f};
    f32x4 Oacc[4];
    #pragma unroll
    for (int nt = 0; nt < 4; nt++) Oacc[nt] = (f32x4)(0.f);

    const int ntiles = i0 / 64 + 17;

    for (int t = 0; t < ntiles; t++) {
        const int j0 = t * 64;
        const int jj0 = j0 + (LQ - 64) - i0;
        {
            const int row = tid >> 2, dbase = (tid & 3) * 16;
            const bf16* src = kv + ((size_t)(j0 + row) * NBAT + b) * (2 * HDIM)
                                 + h * DHEAD + dbase;
            *(uint4*)&Ks[row][dbase]     = *(const uint4*)src;
            *(uint4*)&Ks[row][dbase + 8] = *(const uint4*)(src + 8);
        }
        {
            const int row = tid >> 1, dbase = (tid & 1) * 32;
            const int jj = jj0 + row;
            if (jj < TKEY) {
                const bf16* src = rg + ((size_t)jj * NBAT + b) * HDIM + h * DHEAD + dbase;
                #pragma unroll
                for (int u = 0; u < 4; u++)
                    *(uint4*)&Rs[row][dbase + u * 8] = *(const uint4*)(src + u * 8);
            } else {
                const uint4 z = make_uint4(0, 0, 0, 0);
                #pragma unroll
                for (int u = 0; u < 4; u++)
                    *(uint4*)&Rs[row][dbase + u * 8] = z;
            }
        }
        __syncthreads();
        f32x4 ac[4];
        #pragma unroll
        for (int nt = 0; nt < 4; nt++) {
            ac[nt] = (f32x4)(0.f);
            ac[nt] = __builtin_amdgcn_mfma_f32_16x16x32_bf16(
                         fu0.v, *(const short8*)&Ks[nt * 16 + c16][g * 8], ac[nt], 0, 0, 0);
            ac[nt] = __builtin_amdgcn_mfma_f32_16x16x32_bf16(
                         fu1.v, *(const short8*)&Ks[nt * 16 + c16][32 + g * 8], ac[nt], 0, 0, 0);
        }
        #pragma unroll
        for (int nt = 0; nt < 8; nt++) {
            f32x4 bd = (f32x4)(0.f);
            bd = __builtin_amdgcn_mfma_f32_16x16x32_bf16(
                     fv0.v, *(const short8*)&Rs[nt * 16 + c16][g * 8], bd, 0, 0, 0);
            bd = __builtin_amdgcn_mfma_f32_16x16x32_bf16(
                     fv1.v, *(const short8*)&Rs[nt * 16 + c16][32 + g * 8], bd, 0, 0, 0);
            #pragma unroll
            for (int reg = 0; reg < 4; reg++)
                BDs[dib + reg][nt * 16 + c16] = __float2bfloat16(bd[reg]);
        }
        __syncthreads();
        {
            const int j = tid & 63, dbase = (tid >> 6) * 16;
            const bf16* src = kv + ((size_t)(j0 + j) * NBAT + b) * (2 * HDIM)
                                 + HDIM + h * DHEAD + dbase;
            bf16 tmp[16];
            *(uint4*)&tmp[0] = *(const uint4*)src;
            *(uint4*)&tmp[8] = *(const uint4*)(src + 8);
            #pragma unroll
            for (int e = 0; e < 16; e++) Vt[dbase + e][j] = tmp[e];
        }
        float sv[4][4];
        #pragma unroll
        for (int reg = 0; reg < 4; reg++) {
            const int di = dib + reg;
            const int colbase = 63 - di;
            #pragma unroll
            for (int nt = 0; nt < 4; nt++) {
                const int dj = nt * 16 + c16;
                float s = (ac[nt][reg] +
                           __bfloat162float(BDs[di][colbase + dj])) * SCALE_F;
                if (j0 + dj > i0 + di + MEMLEN) s = -1e30f;
                sv[nt][reg] = s;
            }
        }
        #pragma unroll
        for (int reg = 0; reg < 4; reg++) {
            float tm = fmaxf(fmaxf(sv[0][reg], sv[1][reg]),
                             fmaxf(sv[2][reg], sv[3][reg]));
            #pragma unroll
            for (int mk = 1; mk < 16; mk <<= 1)
                tm = fmaxf(tm, __shfl_xor(tm, mk));
            const float nm = fmaxf(mrow[reg], tm);
            const float alpha = __expf(mrow[reg] - nm);
            float ev[4];
            #pragma unroll
            for (int nt = 0; nt < 4; nt++) ev[nt] = __expf(sv[nt][reg] - nm);
            float ps = ev[0] + ev[1] + ev[2] + ev[3];
            #pragma unroll
            for (int mk = 1; mk < 16; mk <<= 1)
                ps += __shfl_xor(ps, mk);
            lrow[reg] = lrow[reg] * alpha + ps;
            mrow[reg] = nm;
            #pragma unroll
            for (int nt = 0; nt < 4; nt++) {
                Oacc[nt][reg] *= alpha;
                BDs[dib + reg][nt * 16 + c16] = __float2bfloat16(ev[nt]);
            }
        }
        __syncthreads();
        short8 p0 = *(const short8*)&BDs[wave * 16 + c16][g * 8];
        short8 p1 = *(const short8*)&BDs[wave * 16 + c16][32 + g * 8];
        #pragma unroll
        for (int nt = 0; nt < 4; nt++) {
            Oacc[nt] = __builtin_amdgcn_mfma_f32_16x16x32_bf16(
                           p0, *(const short8*)&Vt[nt * 16 + c16][g * 8], Oacc[nt], 0, 0, 0);
            Oacc[nt] = __builtin_amdgcn_mfma_f32_16x16x32_bf16(
                           p1, *(const short8*)&Vt[nt * 16 + c16][32 + g * 8], Oacc[nt], 0, 0, 0);
        }
        __syncthreads();
    }

    float invl[4];
    #pragma unroll
    for (int reg = 0; reg < 4; reg++) invl[reg] = 1.f / lrow[reg];
    #pragma unroll
    for (int nt = 0; nt < 4; nt++)
        #pragma unroll
        for (int reg = 0; reg < 4; reg++)
            vec[((size_t)(i0 + dib + reg) * NBAT + b) * HDIM + h * DHEAD + nt * 16 + c16]
                = __float2bfloat16(Oacc[nt][reg] * invl[reg]);
    if (c16 == 0) {
        #pragma unroll
        for (int reg = 0; reg < 4; reg++) {
            const int idx = ((i0 + dib + reg) * NBAT + b) * NHEAD + h;
            m_arr[idx] = mrow[reg];
            l_arr[idx] = lrow[reg];
        }
    }
}

// ============ attn matrix via MFMA ============
__global__ __launch_bounds__(256)
void attn_mat3_k(const float* __restrict__ q, const bf16* __restrict__ kv,
                 const bf16* __restrict__ rg, const float* __restrict__ ub,
                 const float* __restrict__ vb, const float* __restrict__ m_arr,
                 const float* __restrict__ l_arr, float* __restrict__ attn)
{
    const int i0 = blockIdx.x * 64;
    const int j0 = blockIdx.y * 64;
    const int tid = threadIdx.x;
    if (j0 > i0 + 63 + MEMLEN) {
        for (int e = tid; e < 4096; e += 256)
            attn[(size_t)(i0 + (e >> 6)) * TKEY + j0 + (e & 63)] = 0.f;
        return;
    }
    __shared__ alignas(16) bf16 Ks[64][72];
    __shared__ alignas(16) bf16 Rs[128][72];
    __shared__ alignas(16) bf16 BDs[64][136];
    const int wave = tid >> 6, lane = tid & 63;
    const int g = lane >> 4, c16 = lane & 15;
    const int dib = wave * 16 + g * 4;
    const int jj0 = j0 + (LQ - 64) - i0;
    float psum[4][4] = {};

    for (int bh = 0; bh < NBAT * NHEAD; bh++) {
        const int b = bh >> 4, h = bh & 15;
        Frag8 fu0, fu1, fv0, fv1;
        {
            const float* qrow = q + ((size_t)(i0 + wave * 16 + c16) * NBAT + b) * HDIM + h * DHEAD;
            const float* ubp = ub + h * DHEAD;
            const float* vbp = vb + h * DHEAD;
            #pragma unroll
            for (int e = 0; e < 8; e++) {
                float q0 = qrow[g * 8 + e], q1 = qrow[32 + g * 8 + e];
                fu0.h[e] = __float2bfloat16(q0 + ubp[g * 8 + e]);
                fu1.h[e] = __float2bfloat16(q1 + ubp[32 + g * 8 + e]);
                fv0.h[e] = __float2bfloat16(q0 + vbp[g * 8 + e]);
                fv1.h[e] = __float2bfloat16(q1 + vbp[32 + g * 8 + e]);
            }
        }
        {
            const int row = tid >> 2, dbase = (tid & 3) * 16;
            const bf16* src = kv + ((size_t)(j0 + row) * NBAT + b) * (2 * HDIM)
                                 + h * DHEAD + dbase;
            *(uint4*)&Ks[row][dbase]     = *(const uint4*)src;
            *(uint4*)&Ks[row][dbase + 8] = *(const uint4*)(src + 8);
        }
        {
            const int row = tid >> 1, dbase = (tid & 1) * 32;
            const int jj = jj0 + row;
            if (jj < TKEY) {
                const bf16* src = rg + ((size_t)jj * NBAT + b) * HDIM + h * DHEAD + dbase;
                #pragma unroll
                for (int u = 0; u < 4; u++)
                    *(uint4*)&Rs[row][dbase + u * 8] = *(const uint4*)(src + u * 8);
            } else {
                const uint4 z = make_uint4(0, 0, 0, 0);
                #pragma unroll
                for (int u = 0; u < 4; u++)
                    *(uint4*)&Rs[row][dbase + u * 8] = z;
            }
        }
        __syncthreads();
        f32x4 ac[4];
        #pragma unroll
        for (int nt = 0; nt < 4; nt++) {
            ac[nt] = (f32x4)(0.f);
            ac[nt] = __builtin_amdgcn_mfma_f32_16x16x32_bf16(
                         fu0.v, *(const short8*)&Ks[nt * 16 + c16][g * 8], ac[nt], 0, 0, 0);
            ac[nt] = __builtin_amdgcn_mfma_f32_16x16x32_bf16(
                         fu1.v, *(const short8*)&Ks[nt * 16 + c16][32 + g * 8], ac[nt], 0, 0, 0);
        }
        #pragma unroll
        for (int nt = 0; nt < 8; nt++) {
            f32x4 bd = (f32x4)(0.f);
            bd = __builtin_amdgcn_mfma_f32_16x16x32_bf16(
                     fv0.v, *(const short8*)&Rs[nt * 16 + c16][g * 8], bd, 0, 0, 0);
            bd = __builtin_amdgcn_mfma_f32_16x16x32_bf16(
                     fv1.v, *(const short8*)&Rs[nt * 16 + c16][32 + g * 8], bd, 0, 0, 0);
            #pragma unroll
            for (int reg = 0; reg < 4; reg++)
                BDs[dib + reg][nt * 16 + c16] = __float2bfloat16(bd[reg]);
        }
        #pragma unroll
        for (int reg = 0; reg < 4; reg++) {
            const int di = dib + reg;
            const int colbase = 63 - di;
            const int idx = ((i0 + di) * NBAT + b) * NHEAD + h;
            const float mi = m_arr[idx];
            const float il = 1.f / l_arr[idx];
            #pragma unroll
            for (int nt = 0; nt < 4; nt++) {
                const int dj = nt * 16 + c16;
                float s = (ac[nt][reg] +
                           __bfloat162float(BDs[di][colbase + dj])) * SCALE_F;
                float p = (j0 + dj > i0 + di + MEMLEN) ? 0.f : __expf(s - mi) * il;
                psum[nt][reg] += p;
            }
        }
        __syncthreads();
    }
    const float inv = 1.f / (NBAT * NHEAD);
    #pragma unroll
    for (int nt = 0; nt < 4; nt++)
        #pragma unroll
        for (int reg = 0; reg < 4; reg++)
            attn[(size_t)(i0 + dib + reg) * TKEY + j0 + nt * 16 + c16]
                = psum[nt][reg] * inv;
}

// ---------------- fused residual + LayerNorm ----------------
template<typename T1, typename T2, typename TOUT>
__global__ __launch_bounds__(256)
void ln_k(const T1* __restrict__ a, const T2* __restrict__ c,
          const float* __restrict__ g, const float* __restrict__ bb,
          TOUT* __restrict__ out)
{
    const int row = blockIdx.x;
    const int tid = threadIdx.x;
    const size_t base = (size_t)row * DMOD;
    float vals[4];
    float s = 0.f, sq = 0.f;
    #pragma unroll
    for (int t = 0; t < 4; t++) {
        const int dcol = tid + t * 256;
        float v = ldf(a + base + dcol) + ldf(c + base + dcol);
        vals[t] = v; s += v; sq += v * v;
    }
    __shared__ float rs[256], rq[256];
    rs[tid] = s; rq[tid] = sq;
    __syncthreads();
    for (int st = 128; st > 0; st >>= 1) {
        if (tid < st) { rs[tid] += rs[tid + st]; rq[tid] += rq[tid + st]; }
        __syncthreads();
    }
    const float mean = rs[0] / DMOD;
    const float var = rq[0] / DMOD - mean * mean;
    const float rstd = rsqrtf(fmaxf(var, 0.f) + EPS_F);
    #pragma unroll
    for (int t = 0; t < 4; t++) {
        const int dcol = tid + t * 256;
        float v = (vals[t] - mean) * rstd * g[dcol] + bb[dcol];
        stf(out + base + dcol, v);
    }
}

__global__ void fill_zero_k(float* __restrict__ p, int n) {
    int i = blockIdx.x * 256 + threadIdx.x;
    if (i < n) p[i] = 0.f;
}

extern "C" void kernel_launch(void* const* d_in, const int* in_sizes, int n_in,
                              void* d_out, int out_size, void* d_ws, size_t ws_size,
                              hipStream_t stream)
{
    const float* x    = (const float*)d_in[0];
    const float* pos  = (const float*)d_in[1];
    const float* ub   = (const float*)d_in[2];
    const float* vb   = (const float*)d_in[3];
    const float* memp = (const float*)d_in[4];
    const float* Wq   = (const float*)d_in[5];
    const float* Wkv  = (const float*)d_in[6];
    const float* Wo   = (const float*)d_in[7];
    const float* Wrel = (const float*)d_in[8];
    const float* ln1g = (const float*)d_in[9];
    const float* ln1b = (const float*)d_in[10];
    const float* W1   = (const float*)d_in[11];
    const float* b1   = (const float*)d_in[12];
    const float* W2   = (const float*)d_in[13];
    const float* b2   = (const float*)d_in[14];
    const float* ln2g = (const float*)d_in[15];
    const float* ln2b = (const float*)d_in[16];
    // d_in[17] = mask: analytic (j > i + MEM), unused

    // ---- workspace, lifetime-aliased ----
    char* wsb = (char*)d_ws;
    const size_t MB = 1048576;
    bf16*  kvb   = (bf16*)(wsb + 0);          // [T*B][2H] attention phases
    bf16*  h1    = (bf16*)(wsb + 0);          // [L*B][DFF] FF phase
    bf16*  rb    = (bf16*)(wsb + 16 * MB);    // [T*B][H]  attention phases
    bf16*  aout  = (bf16*)(wsb + 16 * MB);    // [L*B][D]
    bf16*  f2o   = (bf16*)(wsb + 16 * MB);    // [L*B][D]
    bf16*  out1  = (bf16*)(wsb + 20 * MB);    // [L*B][D]
    bf16*  vecb  = (bf16*)(wsb + 24 * MB);    // [L*B][H]
    float* m_arr = (float*)(wsb + 28 * MB);
    float* l_arr = (float*)(wsb + 28 * MB + 131072);
    const size_t ws_need_old = 28 * MB + 262144;
    // new-path extras (fast GEMM operands, bf16)
    bf16*  catc  = (bf16*)(wsb + 30 * MB);    // [T*B][D] = concat(memory,x) bf16, 8MB
    bf16*  posc  = (bf16*)(wsb + 38 * MB);    // [T*B][D] pos bf16, 8MB
    bf16*  wscr  = (bf16*)(wsb + 46 * MB);    // transposed weight scratch, 8MB max
    const size_t ws_need_new = 54 * MB;

    float* outp  = (float*)d_out;
    float* attnp = outp + (size_t)LQ * NBAT * DMOD;
    float* qb    = outp;                      // q scratch (dead before final LN)

    const dim3 blk(256);

    if (ws_size < ws_need_old) {
        fill_zero_k<<<dim3((out_size + 255) / 256), blk, 0, stream>>>(outp, out_size);
        return;
    }

    if (ws_size >= ws_need_new) {
        // ======== fast path: bf16-converted operands + 128x128 global_load_lds GEMM ====
        const int nCat = MEMLEN * NBAT * DMOD;      // 2M elems
        cvt_bf16_k<<<dim3(nCat / 2048), blk, 0, stream>>>(memp, catc, nCat);
        cvt_bf16_k<<<dim3(nCat / 2048), blk, 0, stream>>>(x, catc + (size_t)nCat, nCat);
        const int nPos = TKEY * NBAT * DMOD;        // 4M elems
        cvt_bf16_k<<<dim3(nPos / 2048), blk, 0, stream>>>(pos, posc, nPos);

        // kv = cat @ Wkv -> bf16 [4096 x 2048]
        tcvt_bf16_k<<<dim3(2 * HDIM / 64, DMOD / 64), blk, 0, stream>>>(Wkv, wscr, DMOD, 2 * HDIM);
        mgemm128_k<false, bf16><<<dim3(2 * HDIM / 128, TKEY * NBAT / 128), blk, 0, stream>>>(
            catc, wscr, nullptr, kvb, TKEY * NBAT, 2 * HDIM, DMOD);
        // r = pos @ Wrel -> bf16 [4096 x 1024]
        tcvt_bf16_k<<<dim3(HDIM / 64, DMOD / 64), blk, 0, stream>>>(Wrel, wscr, DMOD, HDIM);
        mgemm128_k<false, bf16><<<dim3(HDIM / 128, TKEY * NBAT / 128), blk, 0, stream>>>(
            posc, wscr, nullptr, rb, TKEY * NBAT, HDIM, DMOD);
        // q = x @ Wq -> fp32 [2048 x 1024]
        tcvt_bf16_k<<<dim3(HDIM / 64, DMOD / 64), blk, 0, stream>>>(Wq, wscr, DMOD, HDIM);
        mgemm128_k<false, float><<<dim3(HDIM / 128, LQ * NBAT / 128), blk, 0, stream>>>(
            catc + (size_t)nCat, wscr, nullptr, qb, LQ * NBAT, HDIM, DMOD);

        flash_attn_k<<<dim3(LQ / 64, NBAT * NHEAD), blk, 0, stream>>>(
            qb, kvb, rb, ub, vb, m_arr, l_arr, vecb);
        attn_mat3_k<<<dim3(LQ / 64, TKEY / 64), blk, 0, stream>>>(
            qb, kvb, rb, ub, vb, m_arr, l_arr, attnp);

        // attn_out = vec @ Wo -> aout (kvb/rb dead)
        tcvt_bf16_k<<<dim3(DMOD / 64, HDIM / 64), blk, 0, stream>>>(Wo, wscr, HDIM, DMOD);
        mgemm128_k<false, bf16><<<dim3(DMOD / 128, LQ * NBAT / 128), blk, 0, stream>>>(
            vecb, wscr, nullptr, aout, LQ * NBAT, DMOD, HDIM);
        ln_k<float, bf16, bf16><<<dim3(LQ * NBAT), blk, 0, stream>>>(x, aout, ln1g, ln1b, out1);
        // h1 = relu(out1 @ W1 + b1)
        tcvt_bf16_k<<<dim3(DFFN / 64, DMOD / 64), blk, 0, stream>>>(W1, wscr, DMOD, DFFN);
        mgemm128_k<true, bf16><<<dim3(DFFN / 128, LQ * NBAT / 128), blk, 0, stream>>>(
            out1, wscr, b1, h1, LQ * NBAT, DFFN, DMOD);
        // ff = h1 @ W2 + b2 -> f2o
        tcvt_bf16_k<<<dim3(DMOD / 64, DFFN / 64), blk, 0, stream>>>(W2, wscr, DFFN, DMOD);
        mgemm128_k<false, bf16><<<dim3(DMOD / 128, LQ * NBAT / 128), blk, 0, stream>>>(
            h1, wscr, b2, f2o, LQ * NBAT, DMOD, DFFN);
        ln_k<bf16, bf16, float><<<dim3(LQ * NBAT), blk, 0, stream>>>(out1, f2o, ln2g, ln2b, outp);
        return;
    }

    // ======== fallback path (verified round-8 structure) ========
    mgemm64_k<float, bf16, false><<<dim3(2 * HDIM / 64, TKEY * NBAT / 64), blk, 0, stream>>>(
        memp, x, MEMLEN * NBAT, Wkv, nullptr, kvb, TKEY * NBAT, 2 * HDIM, DMOD);
    mgemm64_k<float, bf16, false><<<dim3(HDIM / 64, TKEY * NBAT / 64), blk, 0, stream>>>(
        pos, pos, TKEY * NBAT, Wrel, nullptr, rb, TKEY * NBAT, HDIM, DMOD);
    mgemm64_k<float, float, false><<<dim3(HDIM / 64, LQ * NBAT / 64), blk, 0, stream>>>(
        x, x, LQ * NBAT, Wq, nullptr, qb, LQ * NBAT, HDIM, DMOD);

    flash_attn_k<<<dim3(LQ / 64, NBAT * NHEAD), blk, 0, stream>>>(
        qb, kvb, rb, ub, vb, m_arr, l_arr, vecb);
    attn_mat3_k<<<dim3(LQ / 64, TKEY / 64), blk, 0, stream>>>(
        qb, kvb, rb, ub, vb, m_arr, l_arr, attnp);

    mgemm64_k<bf16, bf16, false><<<dim3(DMOD / 64, LQ * NBAT / 64), blk, 0, stream>>>(
        vecb, vecb, LQ * NBAT, Wo, nullptr, aout, LQ * NBAT, DMOD, HDIM);
    ln_k<float, bf16, bf16><<<dim3(LQ * NBAT), blk, 0, stream>>>(x, aout, ln1g, ln1b, out1);
    mgemm64_k<bf16, bf16, true><<<dim3(DFFN / 64, LQ * NBAT / 64), blk, 0, stream>>>(
        out1, out1, LQ * NBAT, W1, b1, h1, LQ * NBAT, DFFN, DMOD);
    mgemm64_k<bf16, bf16, false><<<dim3(DMOD / 64, LQ * NBAT / 64), blk, 0, stream>>>(
        h1, h1, LQ * NBAT, W2, b2, f2o, LQ * NBAT, DMOD, DFFN);
    ln_k<bf16, bf16, float><<<dim3(LQ * NBAT), blk, 0, stream>>>(out1, f2o, ln2g, ln2b, outp);
}

// Round 3
// 569.525 us; speedup vs baseline: 1.1473x; 1.0803x over previous
//
#include <hip/hip_runtime.h>
#include <hip/hip_bf16.h>

using bf16 = __hip_bfloat16;

#define LQ      1024
#define NBAT    2
#define DMOD    1024
#define NHEAD   16
#define DHEAD   64
#define DFFN    4096
#define MEMLEN  1024
#define TKEY    2048
#define HDIM    1024
#define SCALE_F 0.125f
#define EPS_F   1e-5f

typedef __attribute__((ext_vector_type(8))) short short8;
typedef __attribute__((ext_vector_type(4))) float f32x4;

__device__ __forceinline__ float ldf(const float* p) { return *p; }
__device__ __forceinline__ float ldf(const bf16* p) { return __bfloat162float(*p); }
__device__ __forceinline__ void stf(float* p, float v) { *p = v; }
__device__ __forceinline__ void stf(bf16* p, float v) { *p = __float2bfloat16(v); }

// copy 4 elements (converting to bf16) into LDS, 8B store
__device__ __forceinline__ void cpy4(bf16* dst, const float* src) {
    float4 w = *(const float4*)src;
    bf16 t[4] = {__float2bfloat16(w.x), __float2bfloat16(w.y),
                 __float2bfloat16(w.z), __float2bfloat16(w.w)};
    *(uint2*)dst = *(uint2*)t;
}
__device__ __forceinline__ void cpy4(bf16* dst, const bf16* src) {
    *(uint2*)dst = *(const uint2*)src;
}

// async global->LDS 16B: LDS dest is wave-uniform base + lane*16
__device__ __forceinline__ void gload_lds16(const bf16* g, bf16* l) {
    __builtin_amdgcn_global_load_lds(
        (const __attribute__((address_space(1))) unsigned int*)g,
        (__attribute__((address_space(3))) unsigned int*)l, 16, 0, 0);
}

// ---------------- fp32 -> bf16 elementwise convert (8 elems/thread) ----------------
__global__ __launch_bounds__(256)
void cvt_bf16_k(const float* __restrict__ in, bf16* __restrict__ out, int n)
{
    const int i = (blockIdx.x * 256 + threadIdx.x) * 8;
    if (i >= n) return;
    float4 v0 = *(const float4*)(in + i);
    float4 v1 = *(const float4*)(in + i + 4);
    bf16 t[8] = {__float2bfloat16(v0.x), __float2bfloat16(v0.y),
                 __float2bfloat16(v0.z), __float2bfloat16(v0.w),
                 __float2bfloat16(v1.x), __float2bfloat16(v1.y),
                 __float2bfloat16(v1.z), __float2bfloat16(v1.w)};
    *(uint4*)(out + i) = *(uint4*)t;
}

// ---------------- W [K][N] fp32 -> Wt [N][K] bf16 (64x64 tiles) ----------------
__global__ __launch_bounds__(256)
void tcvt_bf16_k(const float* __restrict__ W, bf16* __restrict__ Wt, int K, int N)
{
    __shared__ alignas(16) bf16 tile[64][65];
    const int n0 = blockIdx.x * 64, k0 = blockIdx.y * 64;
    const int tid = threadIdx.x;
    const int r = tid >> 2, cb = (tid & 3) * 16;
    #pragma unroll
    for (int e = 0; e < 16; e++)
        tile[r][cb + e] = __float2bfloat16(W[(size_t)(k0 + r) * N + n0 + cb + e]);
    __syncthreads();
    bf16 t[16];
    #pragma unroll
    for (int e = 0; e < 16; e++) t[e] = tile[cb + e][r];
    bf16* dst = Wt + (size_t)(n0 + r) * K + k0 + cb;
    *(uint4*)dst       = ((uint4*)t)[0];
    *(uint4*)(dst + 8) = ((uint4*)t)[1];
}

// ---------------- MFMA GEMM, 128x128 tile, BK=64, double-buffered LDS ----------------
// A [M][K] bf16 row-major, Bt [N][K] bf16 row-major (pre-transposed weights).
// 256 threads = 4 waves in 2x2; each wave computes a 64x64 output sub-tile.
// 2-phase pipeline: issue next tile's global_load_lds BEFORE ds_read+MFMA of current;
// single barrier per K-step drains both. LDS 64 KB => 2 blocks/CU (= grid cap anyway).
// SPLITS>1: blockIdx.z selects a K-slice; fp32 partials to Cbase + z*M*N (no bias).
template<int SPLITS, bool RELU, typename TOUT>
__global__ __launch_bounds__(256)
void mgemm128_k(const bf16* __restrict__ A, const bf16* __restrict__ Bt,
                const float* __restrict__ bias, TOUT* __restrict__ Cbase,
                int M, int N, int K)
{
    __shared__ alignas(16) bf16 As[2][128 * 64];
    __shared__ alignas(16) bf16 Bs[2][128 * 64];
    const int tid  = threadIdx.x;
    const int wave = tid >> 6, lane = tid & 63;
    const int m0 = blockIdx.y * 128, n0 = blockIdx.x * 128;
    const int g = lane >> 4, c16 = lane & 15;
    const int wr = (wave >> 1) * 64, wc = (wave & 1) * 64;

    const int klen   = K / SPLITS;
    const int kstart = blockIdx.z * klen;
    TOUT* C = Cbase + (size_t)blockIdx.z * M * N;

    f32x4 acc[4][4];
    #pragma unroll
    for (int mi = 0; mi < 4; mi++)
        #pragma unroll
        for (int ni = 0; ni < 4; ni++) acc[mi][ni] = (f32x4)(0.f);

    // staging map: wave w issue q covers rows 32w + 8q + (lane>>3), k-cols (lane&7)*8
    const int r0 = (wave << 5) + (lane >> 3);
    const int cc = (lane & 7) << 3;
    const bf16* agp = A  + (size_t)(m0 + r0) * K + kstart + cc;
    const bf16* bgp = Bt + (size_t)(n0 + r0) * K + kstart + cc;
    const int lb = wave * 2048;

    // prologue: stage K-step 0 into buffer 0
    #pragma unroll
    for (int q = 0; q < 4; q++) {
        gload_lds16(agp + (size_t)(q * 8) * K, &As[0][lb + q * 512]);
        gload_lds16(bgp + (size_t)(q * 8) * K, &Bs[0][lb + q * 512]);
    }
    __syncthreads();

    int cur = 0;
    for (int k0 = 0; k0 < klen; k0 += 64) {
        if (k0 + 64 < klen) {     // issue next-tile loads; they fly under the MFMAs
            #pragma unroll
            for (int q = 0; q < 4; q++) {
                gload_lds16(agp + k0 + 64 + (size_t)(q * 8) * K, &As[cur ^ 1][lb + q * 512]);
                gload_lds16(bgp + k0 + 64 + (size_t)(q * 8) * K, &Bs[cur ^ 1][lb + q * 512]);
            }
        }
        short8 af[4][2], bfr[4][2];
        #pragma unroll
        for (int mi = 0; mi < 4; mi++) {
            af[mi][0] = *(const short8*)&As[cur][(wr + mi * 16 + c16) * 64 + g * 8];
            af[mi][1] = *(const short8*)&As[cur][(wr + mi * 16 + c16) * 64 + 32 + g * 8];
        }
        #pragma unroll
        for (int ni = 0; ni < 4; ni++) {
            bfr[ni][0] = *(const short8*)&Bs[cur][(wc + ni * 16 + c16) * 64 + g * 8];
            bfr[ni][1] = *(const short8*)&Bs[cur][(wc + ni * 16 + c16) * 64 + 32 + g * 8];
        }
        #pragma unroll
        for (int mi = 0; mi < 4; mi++)
            #pragma unroll
            for (int ni = 0; ni < 4; ni++) {
                acc[mi][ni] = __builtin_amdgcn_mfma_f32_16x16x32_bf16(
                                  af[mi][0], bfr[ni][0], acc[mi][ni], 0, 0, 0);
                acc[mi][ni] = __builtin_amdgcn_mfma_f32_16x16x32_bf16(
                                  af[mi][1], bfr[ni][1], acc[mi][ni], 0, 0, 0);
            }
        __syncthreads();   // drains this iter's STAGE (vmcnt) + everyone's ds_reads
        cur ^= 1;
    }

    // epilogue: C/D layout col=lane&15, row=(lane>>4)*4+reg
    const int crow = g * 4;
    #pragma unroll
    for (int ni = 0; ni < 4; ni++) {
        const int n = n0 + wc + ni * 16 + c16;
        const float bv = (SPLITS == 1 && bias) ? bias[n] : 0.f;
        #pragma unroll
        for (int mi = 0; mi < 4; mi++) {
            #pragma unroll
            for (int reg = 0; reg < 4; reg++) {
                const int m = m0 + wr + mi * 16 + crow + reg;
                float v = acc[mi][ni][reg] + bv;
                if (RELU) v = fmaxf(v, 0.f);
                stf(C + (size_t)m * N + n, v);
            }
        }
    }
}

// ---------------- MFMA GEMM, 64x64 tile (fallback path, fp32 weights) ----------------
template<typename TA, typename TOUT, bool RELU>
__global__ __launch_bounds__(256)
void mgemm64_k(const TA* __restrict__ A0, const TA* __restrict__ A1, int rowsplit,
               const float* __restrict__ Bw, const float* __restrict__ bias,
               TOUT* __restrict__ C, int M, int N, int K)
{
    __shared__ alignas(16) bf16 As[64][72];
    __shared__ alignas(16) bf16 Bs[64][72];
    const int tid  = threadIdx.x;
    const int m0   = blockIdx.y * 64;
    const int n0   = blockIdx.x * 64;
    const int wave = tid >> 6, lane = tid & 63;
    const int g = lane >> 4, c16 = lane & 15;

    f32x4 acc[4];
    #pragma unroll
    for (int nt = 0; nt < 4; nt++) acc[nt] = (f32x4)(0.f);

    const int ar = tid >> 2, akc = (tid & 3) * 16;
    const int grow = m0 + ar;
    const TA* Arow = (grow < rowsplit) ? (A0 + (size_t)grow * K)
                                       : (A1 + (size_t)(grow - rowsplit) * K);
    const int bn = tid & 63, bkb = (tid >> 6) * 16;
    const float* Bcol = Bw + n0 + bn;

    for (int k0 = 0; k0 < K; k0 += 64) {
        cpy4(&As[ar][akc],      Arow + k0 + akc);
        cpy4(&As[ar][akc + 4],  Arow + k0 + akc + 4);
        cpy4(&As[ar][akc + 8],  Arow + k0 + akc + 8);
        cpy4(&As[ar][akc + 12], Arow + k0 + akc + 12);
        {
            bf16 t16[16];
            #pragma unroll
            for (int e = 0; e < 16; e++)
                t16[e] = __float2bfloat16(Bcol[(size_t)(k0 + bkb + e) * N]);
            *(uint4*)&Bs[bn][bkb]     = *(uint4*)&t16[0];
            *(uint4*)&Bs[bn][bkb + 8] = *(uint4*)&t16[8];
        }
        __syncthreads();
        const short8 a0 = *(const short8*)&As[wave * 16 + c16][g * 8];
        const short8 a1 = *(const short8*)&As[wave * 16 + c16][32 + g * 8];
        #pragma unroll
        for (int nt = 0; nt < 4; nt++) {
            acc[nt] = __builtin_amdgcn_mfma_f32_16x16x32_bf16(
                          a0, *(const short8*)&Bs[nt * 16 + c16][g * 8], acc[nt], 0, 0, 0);
            acc[nt] = __builtin_amdgcn_mfma_f32_16x16x32_bf16(
                          a1, *(const short8*)&Bs[nt * 16 + c16][32 + g * 8], acc[nt], 0, 0, 0);
        }
        __syncthreads();
    }

    const int crow = (lane >> 4) * 4, ccol = lane & 15;
    #pragma unroll
    for (int nt = 0; nt < 4; nt++) {
        const int n = n0 + nt * 16 + ccol;
        const float bv = bias ? bias[n] : 0.f;
        #pragma unroll
        for (int rr = 0; rr < 4; rr++) {
            const int m = m0 + wave * 16 + crow + rr;
            float v = acc[nt][rr] + bv;
            if (RELU) v = fmaxf(v, 0.f);
            stf(C + (size_t)m * N + n, v);
        }
    }
}

union Frag8 { bf16 h[8]; short8 v; };

// ============ single-sweep online-softmax MFMA attention ============
// itile remap: grid is (x=16 i-tiles, y=32 bh), x-major dispatch pairs block n with
// n+256 on the same CU with the SAME i-tile (256%16==0) -> per-CU work 2*(17..32).
// Pair long with short instead: itile = (by<16) ? bx : 15-bx  -> constant 49/CU.
__global__ __launch_bounds__(256)
void flash_attn_k(const float* __restrict__ q, const bf16* __restrict__ kv,
                  const bf16* __restrict__ rg, const float* __restrict__ ub,
                  const float* __restrict__ vb,
                  float* __restrict__ m_arr, float* __restrict__ l_arr,
                  bf16* __restrict__ vec)
{
    __shared__ alignas(16) bf16 Ks[64][72];
    __shared__ alignas(16) bf16 Rs[128][72];
    __shared__ alignas(16) bf16 BDs[64][136];
    bf16 (*Vt)[72] = (bf16 (*)[72])&Rs[0][0];     // V^T [d][j], aliases Rs

    const int itile = (blockIdx.y < (NBAT * NHEAD / 2))
                          ? blockIdx.x : (gridDim.x - 1 - blockIdx.x);
    const int i0 = itile * 64;
    const int bh = blockIdx.y;
    const int b = bh >> 4, h = bh & 15;
    const int tid = threadIdx.x;
    const int wave = tid >> 6, lane = tid & 63;
    const int g = lane >> 4, c16 = lane & 15;
    const int dib = wave * 16 + g * 4;

    Frag8 fu0, fu1, fv0, fv1;
    {
        const float* qrow = q + ((size_t)(i0 + wave * 16 + c16) * NBAT + b) * HDIM + h * DHEAD;
        const float* ubp = ub + h * DHEAD;
        const float* vbp = vb + h * DHEAD;
        #pragma unroll
        for (int e = 0; e < 8; e++) {
            float q0 = qrow[g * 8 + e], q1 = qrow[32 + g * 8 + e];
            fu0.h[e] = __float2bfloat16(q0 + ubp[g * 8 + e]);
            fu1.h[e] = __float2bfloat16(q1 + ubp[32 + g * 8 + e]);
            fv0.h[e] = __float2bfloat16(q0 + vbp[g * 8 + e]);
            fv1.h[e] = __float2bfloat16(q1 + vbp[32 + g * 8 + e]);
        }
    }

    float mrow[4] = {-3e38f, -3e38f, -3e38f, -3e38f};
    float lrow[4] = {0.f, 0.f, 0.f, 0.f};
    f32x4 Oacc[4];
    #pragma unroll
    for (int nt = 0; nt < 4; nt++) Oacc[nt] = (f32x4)(0.f);

    const int ntiles = i0 / 64 + 17;

    for (int t = 0; t < ntiles; t++) {
        const int j0 = t * 64;
        const int jj0 = j0 + (LQ - 64) - i0;
        {
            const int row = tid >> 2, dbase = (tid & 3) * 16;
            const bf16* src = kv + ((size_t)(j0 + row) * NBAT + b) * (2 * HDIM)
                                 + h * DHEAD + dbase;
            *(uint4*)&Ks[row][dbase]     = *(const uint4*)src;
            *(uint4*)&Ks[row][dbase + 8] = *(const uint4*)(src + 8);
        }
        {
            const int row = tid >> 1, dbase = (tid & 1) * 32;
            const int jj = jj0 + row;
            if (jj < TKEY) {
                const bf16* src = rg + ((size_t)jj * NBAT + b) * HDIM + h * DHEAD + dbase;
                #pragma unroll
                for (int u = 0; u < 4; u++)
                    *(uint4*)&Rs[row][dbase + u * 8] = *(const uint4*)(src + u * 8);
            } else {
                const uint4 z = make_uint4(0, 0, 0, 0);
                #pragma unroll
                for (int u = 0; u < 4; u++)
                    *(uint4*)&Rs[row][dbase + u * 8] = z;
            }
        }
        __syncthreads();
        f32x4 ac[4];
        #pragma unroll
        for (int nt = 0; nt < 4; nt++) {
            ac[nt] = (f32x4)(0.f);
            ac[nt] = __builtin_amdgcn_mfma_f32_16x16x32_bf16(
                         fu0.v, *(const short8*)&Ks[nt * 16 + c16][g * 8], ac[nt], 0, 0, 0);
            ac[nt] = __builtin_amdgcn_mfma_f32_16x16x32_bf16(
                         fu1.v, *(const short8*)&Ks[nt * 16 + c16][32 + g * 8], ac[nt], 0, 0, 0);
        }
        #pragma unroll
        for (int nt = 0; nt < 8; nt++) {
            f32x4 bd = (f32x4)(0.f);
            bd = __builtin_amdgcn_mfma_f32_16x16x32_bf16(
                     fv0.v, *(const short8*)&Rs[nt * 16 + c16][g * 8], bd, 0, 0, 0);
            bd = __builtin_amdgcn_mfma_f32_16x16x32_bf16(
                     fv1.v, *(const short8*)&Rs[nt * 16 + c16][32 + g * 8], bd, 0, 0, 0);
            #pragma unroll
            for (int reg = 0; reg < 4; reg++)
                BDs[dib + reg][nt * 16 + c16] = __float2bfloat16(bd[reg]);
        }
        __syncthreads();
        {
            const int j = tid & 63, dbase = (tid >> 6) * 16;
            const bf16* src = kv + ((size_t)(j0 + j) * NBAT + b) * (2 * HDIM)
                                 + HDIM + h * DHEAD + dbase;
            bf16 tmp[16];
            *(uint4*)&tmp[0] = *(const uint4*)src;
            *(uint4*)&tmp[8] = *(const uint4*)(src + 8);
            #pragma unroll
            for (int e = 0; e < 16; e++) Vt[dbase + e][j] = tmp[e];
        }
        float sv[4][4];
        #pragma unroll
        for (int reg = 0; reg < 4; reg++) {
            const int di = dib + reg;
            const int colbase = 63 - di;
            #pragma unroll
            for (int nt = 0; nt < 4; nt++) {
                const int dj = nt * 16 + c16;
                float s = (ac[nt][reg] +
                           __bfloat162float(BDs[di][colbase + dj])) * SCALE_F;
                if (j0 + dj > i0 + di + MEMLEN) s = -1e30f;
                sv[nt][reg] = s;
            }
        }
        #pragma unroll
        for (int reg = 0; reg < 4; reg++) {
            float tm = fmaxf(fmaxf(sv[0][reg], sv[1][reg]),
                             fmaxf(sv[2][reg], sv[3][reg]));
            #pragma unroll
            for (int mk = 1; mk < 16; mk <<= 1)
                tm = fmaxf(tm, __shfl_xor(tm, mk));
            const float nm = fmaxf(mrow[reg], tm);
            const float alpha = __expf(mrow[reg] - nm);
            float ev[4];
            #pragma unroll
            for (int nt = 0; nt < 4; nt++) ev[nt] = __expf(sv[nt][reg] - nm);
            float ps = ev[0] + ev[1] + ev[2] + ev[3];
            #pragma unroll
            for (int mk = 1; mk < 16; mk <<= 1)
                ps += __shfl_xor(ps, mk);
            lrow[reg] = lrow[reg] * alpha + ps;
            mrow[reg] = nm;
            #pragma unroll
            for (int nt = 0; nt < 4; nt++) {
                Oacc[nt][reg] *= alpha;
                BDs[dib + reg][nt * 16 + c16] = __float2bfloat16(ev[nt]);
            }
        }
        __syncthreads();
        short8 p0 = *(const short8*)&BDs[wave * 16 + c16][g * 8];
        short8 p1 = *(const short8*)&BDs[wave * 16 + c16][32 + g * 8];
        #pragma unroll
        for (int nt = 0; nt < 4; nt++) {
            Oacc[nt] = __builtin_amdgcn_mfma_f32_16x16x32_bf16(
                           p0, *(const short8*)&Vt[nt * 16 + c16][g * 8], Oacc[nt], 0, 0, 0);
            Oacc[nt] = __builtin_amdgcn_mfma_f32_16x16x32_bf16(
                           p1, *(const short8*)&Vt[nt * 16 + c16][32 + g * 8], Oacc[nt], 0, 0, 0);
        }
        __syncthreads();
    }

    float invl[4];
    #pragma unroll
    for (int reg = 0; reg < 4; reg++) invl[reg] = 1.f / lrow[reg];
    #pragma unroll
    for (int nt = 0; nt < 4; nt++)
        #pragma unroll
        for (int reg = 0; reg < 4; reg++)
            vec[((size_t)(i0 + dib + reg) * NBAT + b) * HDIM + h * DHEAD + nt * 16 + c16]
                = __float2bfloat16(Oacc[nt][reg] * invl[reg]);
    if (c16 == 0) {
        #pragma unroll
        for (int reg = 0; reg < 4; reg++) {
            const int idx = ((i0 + dib + reg) * NBAT + b) * NHEAD + h;
            m_arr[idx] = mrow[reg];
            l_arr[idx] = lrow[reg];
        }
    }
}

// ============ attn matrix via MFMA ============
__global__ __launch_bounds__(256)
void attn_mat3_k(const float* __restrict__ q, const bf16* __restrict__ kv,
                 const bf16* __restrict__ rg, const float* __restrict__ ub,
                 const float* __restrict__ vb, const float* __restrict__ m_arr,
                 const float* __restrict__ l_arr, float* __restrict__ attn)
{
    const int i0 = blockIdx.x * 64;
    const int j0 = blockIdx.y * 64;
    const int tid = threadIdx.x;
    if (j0 > i0 + 63 + MEMLEN) {
        for (int e = tid; e < 4096; e += 256)
            attn[(size_t)(i0 + (e >> 6)) * TKEY + j0 + (e & 63)] = 0.f;
        return;
    }
    __shared__ alignas(16) bf16 Ks[64][72];
    __shared__ alignas(16) bf16 Rs[128][72];
    __shared__ alignas(16) bf16 BDs[64][136];
    const int wave = tid >> 6, lane = tid & 63;
    const int g = lane >> 4, c16 = lane & 15;
    const int dib = wave * 16 + g * 4;
    const int jj0 = j0 + (LQ - 64) - i0;
    float psum[4][4] = {};

    for (int bh = 0; bh < NBAT * NHEAD; bh++) {
        const int b = bh >> 4, h = bh & 15;
        Frag8 fu0, fu1, fv0, fv1;
        {
            const float* qrow = q + ((size_t)(i0 + wave * 16 + c16) * NBAT + b) * HDIM + h * DHEAD;
            const float* ubp = ub + h * DHEAD;
            const float* vbp = vb + h * DHEAD;
            #pragma unroll
            for (int e = 0; e < 8; e++) {
                float q0 = qrow[g * 8 + e], q1 = qrow[32 + g * 8 + e];
                fu0.h[e] = __float2bfloat16(q0 + ubp[g * 8 + e]);
                fu1.h[e] = __float2bfloat16(q1 + ubp[32 + g * 8 + e]);
                fv0.h[e] = __float2bfloat16(q0 + vbp[g * 8 + e]);
                fv1.h[e] = __float2bfloat16(q1 + vbp[32 + g * 8 + e]);
            }
        }
        {
            const int row = tid >> 2, dbase = (tid & 3) * 16;
            const bf16* src = kv + ((size_t)(j0 + row) * NBAT + b) * (2 * HDIM)
                                 + h * DHEAD + dbase;
            *(uint4*)&Ks[row][dbase]     = *(const uint4*)src;
            *(uint4*)&Ks[row][dbase + 8] = *(const uint4*)(src + 8);
        }
        {
            const int row = tid >> 1, dbase = (tid & 1) * 32;
            const int jj = jj0 + row;
            if (jj < TKEY) {
                const bf16* src = rg + ((size_t)jj * NBAT + b) * HDIM + h * DHEAD + dbase;
                #pragma unroll
                for (int u = 0; u < 4; u++)
                    *(uint4*)&Rs[row][dbase + u * 8] = *(const uint4*)(src + u * 8);
            } else {
                const uint4 z = make_uint4(0, 0, 0, 0);
                #pragma unroll
                for (int u = 0; u < 4; u++)
                    *(uint4*)&Rs[row][dbase + u * 8] = z;
            }
        }
        __syncthreads();
        f32x4 ac[4];
        #pragma unroll
        for (int nt = 0; nt < 4; nt++) {
            ac[nt] = (f32x4)(0.f);
            ac[nt] = __builtin_amdgcn_mfma_f32_16x16x32_bf16(
                         fu0.v, *(const short8*)&Ks[nt * 16 + c16][g * 8], ac[nt], 0, 0, 0);
            ac[nt] = __builtin_amdgcn_mfma_f32_16x16x32_bf16(
                         fu1.v, *(const short8*)&Ks[nt * 16 + c16][32 + g * 8], ac[nt], 0, 0, 0);
        }
        #pragma unroll
        for (int nt = 0; nt < 8; nt++) {
            f32x4 bd = (f32x4)(0.f);
            bd = __builtin_amdgcn_mfma_f32_16x16x32_bf16(
                     fv0.v, *(const short8*)&Rs[nt * 16 + c16][g * 8], bd, 0, 0, 0);
            bd = __builtin_amdgcn_mfma_f32_16x16x32_bf16(
                     fv1.v, *(const short8*)&Rs[nt * 16 + c16][32 + g * 8], bd, 0, 0, 0);
            #pragma unroll
            for (int reg = 0; reg < 4; reg++)
                BDs[dib + reg][nt * 16 + c16] = __float2bfloat16(bd[reg]);
        }
        #pragma unroll
        for (int reg = 0; reg < 4; reg++) {
            const int di = dib + reg;
            const int colbase = 63 - di;
            const int idx = ((i0 + di) * NBAT + b) * NHEAD + h;
            const float mi = m_arr[idx];
            const float il = 1.f / l_arr[idx];
            #pragma unroll
            for (int nt = 0; nt < 4; nt++) {
                const int dj = nt * 16 + c16;
                float s = (ac[nt][reg] +
                           __bfloat162float(BDs[di][colbase + dj])) * SCALE_F;
                float p = (j0 + dj > i0 + di + MEMLEN) ? 0.f : __expf(s - mi) * il;
                psum[nt][reg] += p;
            }
        }
        __syncthreads();
    }
    const float inv = 1.f / (NBAT * NHEAD);
    #pragma unroll
    for (int nt = 0; nt < 4; nt++)
        #pragma unroll
        for (int reg = 0; reg < 4; reg++)
            attn[(size_t)(i0 + dib + reg) * TKEY + j0 + nt * 16 + c16]
                = psum[nt][reg] * inv;
}

// ---------------- fused residual + LayerNorm ----------------
template<typename T1, typename T2, typename TOUT>
__global__ __launch_bounds__(256)
void ln_k(const T1* __restrict__ a, const T2* __restrict__ c,
          const float* __restrict__ g, const float* __restrict__ bb,
          TOUT* __restrict__ out)
{
    const int row = blockIdx.x;
    const int tid = threadIdx.x;
    const size_t base = (size_t)row * DMOD;
    float vals[4];
    float s = 0.f, sq = 0.f;
    #pragma unroll
    for (int t = 0; t < 4; t++) {
        const int dcol = tid + t * 256;
        float v = ldf(a + base + dcol) + ldf(c + base + dcol);
        vals[t] = v; s += v; sq += v * v;
    }
    __shared__ float rs[256], rq[256];
    rs[tid] = s; rq[tid] = sq;
    __syncthreads();
    for (int st = 128; st > 0; st >>= 1) {
        if (tid < st) { rs[tid] += rs[tid + st]; rq[tid] += rq[tid + st]; }
        __syncthreads();
    }
    const float mean = rs[0] / DMOD;
    const float var = rq[0] / DMOD - mean * mean;
    const float rstd = rsqrtf(fmaxf(var, 0.f) + EPS_F);
    #pragma unroll
    for (int t = 0; t < 4; t++) {
        const int dcol = tid + t * 256;
        float v = (vals[t] - mean) * rstd * g[dcol] + bb[dcol];
        stf(out + base + dcol, v);
    }
}

// ---------------- residual + NP split-K fp32 partials (+optional bias) + LayerNorm ----
template<typename TA, int NP, bool HASB, typename TOUT>
__global__ __launch_bounds__(256)
void lnp_k(const TA* __restrict__ a, const float* __restrict__ part, size_t pstride,
           const float* __restrict__ biasvec, const float* __restrict__ g,
           const float* __restrict__ bb, TOUT* __restrict__ out)
{
    const int row = blockIdx.x;
    const int tid = threadIdx.x;
    const size_t base = (size_t)row * DMOD;
    float vals[4];
    float s = 0.f, sq = 0.f;
    #pragma unroll
    for (int t = 0; t < 4; t++) {
        const int dcol = tid + t * 256;
        float v = ldf(a + base + dcol);
        #pragma unroll
        for (int p = 0; p < NP; p++) v += part[(size_t)p * pstride + base + dcol];
        if (HASB) v += biasvec[dcol];
        vals[t] = v; s += v; sq += v * v;
    }
    __shared__ float rs[256], rq[256];
    rs[tid] = s; rq[tid] = sq;
    __syncthreads();
    for (int st = 128; st > 0; st >>= 1) {
        if (tid < st) { rs[tid] += rs[tid + st]; rq[tid] += rq[tid + st]; }
        __syncthreads();
    }
    const float mean = rs[0] / DMOD;
    const float var = rq[0] / DMOD - mean * mean;
    const float rstd = rsqrtf(fmaxf(var, 0.f) + EPS_F);
    #pragma unroll
    for (int t = 0; t < 4; t++) {
        const int dcol = tid + t * 256;
        float v = (vals[t] - mean) * rstd * g[dcol] + bb[dcol];
        stf(out + base + dcol, v);
    }
}

__global__ void fill_zero_k(float* __restrict__ p, int n) {
    int i = blockIdx.x * 256 + threadIdx.x;
    if (i < n) p[i] = 0.f;
}

extern "C" void kernel_launch(void* const* d_in, const int* in_sizes, int n_in,
                              void* d_out, int out_size, void* d_ws, size_t ws_size,
                              hipStream_t stream)
{
    const float* x    = (const float*)d_in[0];
    const float* pos  = (const float*)d_in[1];
    const float* ub   = (const float*)d_in[2];
    const float* vb   = (const float*)d_in[3];
    const float* memp = (const float*)d_in[4];
    const float* Wq   = (const float*)d_in[5];
    const float* Wkv  = (const float*)d_in[6];
    const float* Wo   = (const float*)d_in[7];
    const float* Wrel = (const float*)d_in[8];
    const float* ln1g = (const float*)d_in[9];
    const float* ln1b = (const float*)d_in[10];
    const float* W1   = (const float*)d_in[11];
    const float* b1   = (const float*)d_in[12];
    const float* W2   = (const float*)d_in[13];
    const float* b2   = (const float*)d_in[14];
    const float* ln2g = (const float*)d_in[15];
    const float* ln2b = (const float*)d_in[16];
    // d_in[17] = mask: analytic (j > i + MEM), unused

    // ---- workspace, lifetime-aliased ----
    char* wsb = (char*)d_ws;
    const size_t MB = 1048576;
    bf16*  kvb   = (bf16*)(wsb + 0);          // [T*B][2H] attention phases
    bf16*  h1    = (bf16*)(wsb + 0);          // [L*B][DFF] FF phase
    bf16*  rb    = (bf16*)(wsb + 16 * MB);    // [T*B][H]  attention phases
    bf16*  aout  = (bf16*)(wsb + 16 * MB);    // [L*B][D]  (fallback path only)
    bf16*  f2o   = (bf16*)(wsb + 16 * MB);    // [L*B][D]  (fallback path only)
    bf16*  out1  = (bf16*)(wsb + 20 * MB);    // [L*B][D]
    bf16*  vecb  = (bf16*)(wsb + 24 * MB);    // [L*B][H]
    float* m_arr = (float*)(wsb + 28 * MB);
    float* l_arr = (float*)(wsb + 28 * MB + 131072);
    const size_t ws_need_old = 28 * MB + 262144;
    // fast-path extras
    bf16*  catc  = (bf16*)(wsb + 30 * MB);    // [T*B][D] concat bf16, 8MB (dead after q GEMM)
    bf16*  posc  = (bf16*)(wsb + 38 * MB);    // [T*B][D] pos bf16, 8MB (dead after r GEMM)
    float* part2 = (float*)(wsb + 30 * MB);   // 2x [L*B][D] fp32 split-K partials, 16MB
                                              // (reuses catc/posc region post-attention)
    bf16*  wscr  = (bf16*)(wsb + 46 * MB);    // transposed weight scratch, 8MB max
    const size_t ws_need_new = 54 * MB;

    float* outp  = (float*)d_out;
    float* attnp = outp + (size_t)LQ * NBAT * DMOD;
    float* qb    = outp;                      // q scratch (dead before final LN)

    const dim3 blk(256);
    const size_t PSTRIDE = (size_t)LQ * NBAT * DMOD;   // partial slice stride (elems)

    if (ws_size < ws_need_old) {
        fill_zero_k<<<dim3((out_size + 255) / 256), blk, 0, stream>>>(outp, out_size);
        return;
    }

    if (ws_size >= ws_need_new) {
        // ======== fast path: bf16 operands + dbuf 128x128 GEMM + split-K tails ========
        const int nCat = MEMLEN * NBAT * DMOD;      // 2M elems
        cvt_bf16_k<<<dim3(nCat / 2048), blk, 0, stream>>>(memp, catc, nCat);
        cvt_bf16_k<<<dim3(nCat / 2048), blk, 0, stream>>>(x, catc + (size_t)nCat, nCat);
        const int nPos = TKEY * NBAT * DMOD;        // 4M elems
        cvt_bf16_k<<<dim3(nPos / 2048), blk, 0, stream>>>(pos, posc, nPos);

        // kv = cat @ Wkv -> bf16 [4096 x 2048]
        tcvt_bf16_k<<<dim3(2 * HDIM / 64, DMOD / 64), blk, 0, stream>>>(Wkv, wscr, DMOD, 2 * HDIM);
        mgemm128_k<1, false, bf16><<<dim3(2 * HDIM / 128, TKEY * NBAT / 128, 1), blk, 0, stream>>>(
            catc, wscr, nullptr, kvb, TKEY * NBAT, 2 * HDIM, DMOD);
        // r = pos @ Wrel -> bf16 [4096 x 1024]
        tcvt_bf16_k<<<dim3(HDIM / 64, DMOD / 64), blk, 0, stream>>>(Wrel, wscr, DMOD, HDIM);
        mgemm128_k<1, false, bf16><<<dim3(HDIM / 128, TKEY * NBAT / 128, 1), blk, 0, stream>>>(
            posc, wscr, nullptr, rb, TKEY * NBAT, HDIM, DMOD);
        // q = x @ Wq -> fp32 [2048 x 1024]
        tcvt_bf16_k<<<dim3(HDIM / 64, DMOD / 64), blk, 0, stream>>>(Wq, wscr, DMOD, HDIM);
        mgemm128_k<1, false, float><<<dim3(HDIM / 128, LQ * NBAT / 128, 1), blk, 0, stream>>>(
            catc + (size_t)nCat, wscr, nullptr, qb, LQ * NBAT, HDIM, DMOD);

        flash_attn_k<<<dim3(LQ / 64, NBAT * NHEAD), blk, 0, stream>>>(
            qb, kvb, rb, ub, vb, m_arr, l_arr, vecb);
        attn_mat3_k<<<dim3(LQ / 64, TKEY / 64), blk, 0, stream>>>(
            qb, kvb, rb, ub, vb, m_arr, l_arr, attnp);

        // attn_out = vec @ Wo : split-K=2 fp32 partials (catc/posc dead now)
        tcvt_bf16_k<<<dim3(DMOD / 64, HDIM / 64), blk, 0, stream>>>(Wo, wscr, HDIM, DMOD);
        mgemm128_k<2, false, float><<<dim3(DMOD / 128, LQ * NBAT / 128, 2), blk, 0, stream>>>(
            vecb, wscr, nullptr, part2, LQ * NBAT, DMOD, HDIM);
        // out1 = LN(x + p0 + p1)
        lnp_k<float, 2, false, bf16><<<dim3(LQ * NBAT), blk, 0, stream>>>(
            x, part2, PSTRIDE, nullptr, ln1g, ln1b, out1);
        // h1 = relu(out1 @ W1 + b1)
        tcvt_bf16_k<<<dim3(DFFN / 64, DMOD / 64), blk, 0, stream>>>(W1, wscr, DMOD, DFFN);
        mgemm128_k<1, true, bf16><<<dim3(DFFN / 128, LQ * NBAT / 128, 1), blk, 0, stream>>>(
            out1, wscr, b1, h1, LQ * NBAT, DFFN, DMOD);
        // ff partials = h1 @ W2 : split-K=2 (Wo partials dead after ln1)
        tcvt_bf16_k<<<dim3(DMOD / 64, DFFN / 64), blk, 0, stream>>>(W2, wscr, DFFN, DMOD);
        mgemm128_k<2, false, float><<<dim3(DMOD / 128, LQ * NBAT / 128, 2), blk, 0, stream>>>(
            h1, wscr, nullptr, part2, LQ * NBAT, DMOD, DFFN);
        // out = LN(out1 + p0 + p1 + b2)
        lnp_k<bf16, 2, true, float><<<dim3(LQ * NBAT), blk, 0, stream>>>(
            out1, part2, PSTRIDE, b2, ln2g, ln2b, outp);
        return;
    }

    // ======== fallback path (verified round-8 structure) ========
    mgemm64_k<float, bf16, false><<<dim3(2 * HDIM / 64, TKEY * NBAT / 64), blk, 0, stream>>>(
        memp, x, MEMLEN * NBAT, Wkv, nullptr, kvb, TKEY * NBAT, 2 * HDIM, DMOD);
    mgemm64_k<float, bf16, false><<<dim3(HDIM / 64, TKEY * NBAT / 64), blk, 0, stream>>>(
        pos, pos, TKEY * NBAT, Wrel, nullptr, rb, TKEY * NBAT, HDIM, DMOD);
    mgemm64_k<float, float, false><<<dim3(HDIM / 64, LQ * NBAT / 64), blk, 0, stream>>>(
        x, x, LQ * NBAT, Wq, nullptr, qb, LQ * NBAT, HDIM, DMOD);

    flash_attn_k<<<dim3(LQ / 64, NBAT * NHEAD), blk, 0, stream>>>(
        qb, kvb, rb, ub, vb, m_arr, l_arr, vecb);
    attn_mat3_k<<<dim3(LQ / 64, TKEY / 64), blk, 0, stream>>>(
        qb, kvb, rb, ub, vb, m_arr, l_arr, attnp);

    mgemm64_k<bf16, bf16, false><<<dim3(DMOD / 64, LQ * NBAT / 64), blk, 0, stream>>>(
        vecb, vecb, LQ * NBAT, Wo, nullptr, aout, LQ * NBAT, DMOD, HDIM);
    ln_k<float, bf16, bf16><<<dim3(LQ * NBAT), blk, 0, stream>>>(x, aout, ln1g, ln1b, out1);
    mgemm64_k<bf16, bf16, true><<<dim3(DFFN / 64, LQ * NBAT / 64), blk, 0, stream>>>(
        out1, out1, LQ * NBAT, W1, b1, h1, LQ * NBAT, DFFN, DMOD);
    mgemm64_k<bf16, bf16, false><<<dim3(DMOD / 64, LQ * NBAT / 64), blk, 0, stream>>>(
        h1, h1, LQ * NBAT, W2, b2, f2o, LQ * NBAT, DMOD, DFFN);
    ln_k<bf16, bf16, float><<<dim3(LQ * NBAT), blk, 0, stream>>>(out1, f2o, ln2g, ln2b, outp);
}

// Round 4
// 569.456 us; speedup vs baseline: 1.1474x; 1.0001x over previous
//
#include <hip/hip_runtime.h>
#include <hip/hip_bf16.h>

using bf16 = __hip_bfloat16;

#define LQ      1024
#define NBAT    2
#define DMOD    1024
#define NHEAD   16
#define DHEAD   64
#define DFFN    4096
#define MEMLEN  1024
#define TKEY    2048
#define HDIM    1024
#define SCALE_F 0.125f
#define EPS_F   1e-5f

typedef __attribute__((ext_vector_type(8))) short short8;
typedef __attribute__((ext_vector_type(4))) float f32x4;

__device__ __forceinline__ float ldf(const float* p) { return *p; }
__device__ __forceinline__ float ldf(const bf16* p) { return __bfloat162float(*p); }
__device__ __forceinline__ void stf(float* p, float v) { *p = v; }
__device__ __forceinline__ void stf(bf16* p, float v) { *p = __float2bfloat16(v); }

// copy 4 elements (converting to bf16) into LDS, 8B store
__device__ __forceinline__ void cpy4(bf16* dst, const float* src) {
    float4 w = *(const float4*)src;
    bf16 t[4] = {__float2bfloat16(w.x), __float2bfloat16(w.y),
                 __float2bfloat16(w.z), __float2bfloat16(w.w)};
    *(uint2*)dst = *(uint2*)t;
}
__device__ __forceinline__ void cpy4(bf16* dst, const bf16* src) {
    *(uint2*)dst = *(const uint2*)src;
}

// async global->LDS 16B: LDS dest is wave-uniform base + lane*16
__device__ __forceinline__ void gload_lds16(const bf16* g, bf16* l) {
    __builtin_amdgcn_global_load_lds(
        (const __attribute__((address_space(1))) unsigned int*)g,
        (__attribute__((address_space(3))) unsigned int*)l, 16, 0, 0);
}

// ---------------- fused fp32 -> bf16 elementwise converts (3 ranges, 1 launch) -------
__global__ __launch_bounds__(256)
void cvt3_bf16_k(const float* __restrict__ s0, bf16* __restrict__ d0, int n0,
                 const float* __restrict__ s1, bf16* __restrict__ d1, int n1,
                 const float* __restrict__ s2, bf16* __restrict__ d2, int n2)
{
    int i = (blockIdx.x * 256 + threadIdx.x) * 8;
    const float* s; bf16* d;
    if (i < n0)           { s = s0;            d = d0;            }
    else if (i < n0 + n1) { s = s1 + (i - n0) - i + i; d = d1; s = s1; i -= n0; }
    else if (i < n0 + n1 + n2) { s = s2; d = d2; i -= n0 + n1; }
    else return;
    float4 v0 = *(const float4*)(s + i);
    float4 v1 = *(const float4*)(s + i + 4);
    bf16 t[8] = {__float2bfloat16(v0.x), __float2bfloat16(v0.y),
                 __float2bfloat16(v0.z), __float2bfloat16(v0.w),
                 __float2bfloat16(v1.x), __float2bfloat16(v1.y),
                 __float2bfloat16(v1.z), __float2bfloat16(v1.w)};
    *(uint4*)(d + i) = *(uint4*)t;
}

// ---------------- W [K][N] fp32 -> Wt [N][K] bf16, 64x64 tile body ----------------
__device__ __forceinline__ void tcvt_tile(const float* __restrict__ W,
                                          bf16* __restrict__ Wt,
                                          int K, int N, int n0, int k0, int tid,
                                          bf16 (*tile)[65])
{
    const int r = tid >> 2, cb = (tid & 3) * 16;
    #pragma unroll
    for (int e = 0; e < 16; e++)
        tile[r][cb + e] = __float2bfloat16(W[(size_t)(k0 + r) * N + n0 + cb + e]);
    __syncthreads();
    bf16 t[16];
    #pragma unroll
    for (int e = 0; e < 16; e++) t[e] = tile[cb + e][r];
    bf16* dst = Wt + (size_t)(n0 + r) * K + k0 + cb;
    *(uint4*)dst       = ((uint4*)t)[0];
    *(uint4*)(dst + 8) = ((uint4*)t)[1];
}

__global__ __launch_bounds__(256)
void tcvt_bf16_k(const float* __restrict__ W, bf16* __restrict__ Wt, int K, int N)
{
    __shared__ alignas(16) bf16 tile[64][65];
    tcvt_tile(W, Wt, K, N, blockIdx.x * 64, blockIdx.y * 64, threadIdx.x, tile);
}

// batched transpose-convert: Wkv(1024x2048) + Wrel(1024x1024) + Wq(1024x1024), K=1024
__global__ __launch_bounds__(256)
void tcvt3_k(const float* __restrict__ Wkv_, bf16* __restrict__ dkv,
             const float* __restrict__ Wrel_, bf16* __restrict__ dr,
             const float* __restrict__ Wq_, bf16* __restrict__ dq)
{
    __shared__ alignas(16) bf16 tile[64][65];
    int bid = blockIdx.x;
    const float* W; bf16* Wt; int N;
    if (bid < 512)      { W = Wkv_;  Wt = dkv; N = 2048; }
    else if (bid < 768) { W = Wrel_; Wt = dr;  N = 1024; bid -= 512; }
    else                { W = Wq_;   Wt = dq;  N = 1024; bid -= 768; }
    const int nb = N / 64;
    tcvt_tile(W, Wt, DMOD, N, (bid % nb) * 64, (bid / nb) * 64, threadIdx.x, tile);
}

// ---------------- MFMA GEMM, 128x128 tile, BK=64, dbuf + counted vmcnt (T4) ---------
// A [M][K] bf16 row-major, Bt [N][K] bf16 row-major (pre-transposed weights).
// 256 threads = 4 waves in 2x2; each wave computes a 64x64 output sub-tile.
// Pipeline per K-step: STAGE(next buf) -> s_waitcnt vmcnt(8) (cur tile landed; next 8
// stay in flight ACROSS the barrier) -> s_barrier -> ds_read+MFMA -> s_barrier.
// vmcnt(8) is safe even with stray vmem ops: the newest 8 are always the next tile.
// SPLITS>1: blockIdx.z selects a K-slice; fp32 partials to Cbase + z*M*N (no bias).
template<int SPLITS, bool RELU, typename TOUT>
__global__ __launch_bounds__(256)
void mgemm128_k(const bf16* __restrict__ A, const bf16* __restrict__ Bt,
                const float* __restrict__ bias, TOUT* __restrict__ Cbase,
                int M, int N, int K)
{
    __shared__ alignas(16) bf16 As[2][128 * 64];
    __shared__ alignas(16) bf16 Bs[2][128 * 64];
    const int tid  = threadIdx.x;
    const int wave = tid >> 6, lane = tid & 63;
    const int m0 = blockIdx.y * 128, n0 = blockIdx.x * 128;
    const int g = lane >> 4, c16 = lane & 15;
    const int wr = (wave >> 1) * 64, wc = (wave & 1) * 64;

    const int klen   = K / SPLITS;
    const int kstart = blockIdx.z * klen;
    TOUT* C = Cbase + (size_t)blockIdx.z * M * N;

    f32x4 acc[4][4];
    #pragma unroll
    for (int mi = 0; mi < 4; mi++)
        #pragma unroll
        for (int ni = 0; ni < 4; ni++) acc[mi][ni] = (f32x4)(0.f);

    // staging map: wave w issue q covers rows 32w + 8q + (lane>>3), k-cols (lane&7)*8
    const int r0 = (wave << 5) + (lane >> 3);
    const int cc = (lane & 7) << 3;
    const bf16* agp = A  + (size_t)(m0 + r0) * K + kstart + cc;
    const bf16* bgp = Bt + (size_t)(n0 + r0) * K + kstart + cc;
    const int lb = wave * 2048;

    // prologue: stage K-step 0 into buffer 0 (8 vmem ops/wave in flight)
    #pragma unroll
    for (int q = 0; q < 4; q++) {
        gload_lds16(agp + (size_t)(q * 8) * K, &As[0][lb + q * 512]);
        gload_lds16(bgp + (size_t)(q * 8) * K, &Bs[0][lb + q * 512]);
    }

    int cur = 0;
    for (int k0 = 0; k0 < klen; k0 += 64) {
        if (k0 + 64 < klen) {   // issue next tile; it stays in flight across barriers
            #pragma unroll
            for (int q = 0; q < 4; q++) {
                gload_lds16(agp + k0 + 64 + (size_t)(q * 8) * K, &As[cur ^ 1][lb + q * 512]);
                gload_lds16(bgp + k0 + 64 + (size_t)(q * 8) * K, &Bs[cur ^ 1][lb + q * 512]);
            }
            asm volatile("s_waitcnt vmcnt(8)" ::: "memory");
        } else {
            asm volatile("s_waitcnt vmcnt(0)" ::: "memory");
        }
        __builtin_amdgcn_s_barrier();          // cur buffer ready on all waves
        short8 af[4][2], bfr[4][2];
        #pragma unroll
        for (int mi = 0; mi < 4; mi++) {
            af[mi][0] = *(const short8*)&As[cur][(wr + mi * 16 + c16) * 64 + g * 8];
            af[mi][1] = *(const short8*)&As[cur][(wr + mi * 16 + c16) * 64 + 32 + g * 8];
        }
        #pragma unroll
        for (int ni = 0; ni < 4; ni++) {
            bfr[ni][0] = *(const short8*)&Bs[cur][(wc + ni * 16 + c16) * 64 + g * 8];
            bfr[ni][1] = *(const short8*)&Bs[cur][(wc + ni * 16 + c16) * 64 + 32 + g * 8];
        }
        #pragma unroll
        for (int mi = 0; mi < 4; mi++)
            #pragma unroll
            for (int ni = 0; ni < 4; ni++) {
                acc[mi][ni] = __builtin_amdgcn_mfma_f32_16x16x32_bf16(
                                  af[mi][0], bfr[ni][0], acc[mi][ni], 0, 0, 0);
                acc[mi][ni] = __builtin_amdgcn_mfma_f32_16x16x32_bf16(
                                  af[mi][1], bfr[ni][1], acc[mi][ni], 0, 0, 0);
            }
        __builtin_amdgcn_s_barrier();          // all waves done reading cur; next iter
        cur ^= 1;                              // may overwrite it
    }

    // epilogue: C/D layout col=lane&15, row=(lane>>4)*4+reg
    const int crow = g * 4;
    #pragma unroll
    for (int ni = 0; ni < 4; ni++) {
        const int n = n0 + wc + ni * 16 + c16;
        const float bv = (SPLITS == 1 && bias) ? bias[n] : 0.f;
        #pragma unroll
        for (int mi = 0; mi < 4; mi++) {
            #pragma unroll
            for (int reg = 0; reg < 4; reg++) {
                const int m = m0 + wr + mi * 16 + crow + reg;
                float v = acc[mi][ni][reg] + bv;
                if (RELU) v = fmaxf(v, 0.f);
                stf(C + (size_t)m * N + n, v);
            }
        }
    }
}

// ---------------- MFMA GEMM, 64x64 tile (fallback path, fp32 weights) ----------------
template<typename TA, typename TOUT, bool RELU>
__global__ __launch_bounds__(256)
void mgemm64_k(const TA* __restrict__ A0, const TA* __restrict__ A1, int rowsplit,
               const float* __restrict__ Bw, const float* __restrict__ bias,
               TOUT* __restrict__ C, int M, int N, int K)
{
    __shared__ alignas(16) bf16 As[64][72];
    __shared__ alignas(16) bf16 Bs[64][72];
    const int tid  = threadIdx.x;
    const int m0   = blockIdx.y * 64;
    const int n0   = blockIdx.x * 64;
    const int wave = tid >> 6, lane = tid & 63;
    const int g = lane >> 4, c16 = lane & 15;

    f32x4 acc[4];
    #pragma unroll
    for (int nt = 0; nt < 4; nt++) acc[nt] = (f32x4)(0.f);

    const int ar = tid >> 2, akc = (tid & 3) * 16;
    const int grow = m0 + ar;
    const TA* Arow = (grow < rowsplit) ? (A0 + (size_t)grow * K)
                                       : (A1 + (size_t)(grow - rowsplit) * K);
    const int bn = tid & 63, bkb = (tid >> 6) * 16;
    const float* Bcol = Bw + n0 + bn;

    for (int k0 = 0; k0 < K; k0 += 64) {
        cpy4(&As[ar][akc],      Arow + k0 + akc);
        cpy4(&As[ar][akc + 4],  Arow + k0 + akc + 4);
        cpy4(&As[ar][akc + 8],  Arow + k0 + akc + 8);
        cpy4(&As[ar][akc + 12], Arow + k0 + akc + 12);
        {
            bf16 t16[16];
            #pragma unroll
            for (int e = 0; e < 16; e++)
                t16[e] = __float2bfloat16(Bcol[(size_t)(k0 + bkb + e) * N]);
            *(uint4*)&Bs[bn][bkb]     = *(uint4*)&t16[0];
            *(uint4*)&Bs[bn][bkb + 8] = *(uint4*)&t16[8];
        }
        __syncthreads();
        const short8 a0 = *(const short8*)&As[wave * 16 + c16][g * 8];
        const short8 a1 = *(const short8*)&As[wave * 16 + c16][32 + g * 8];
        #pragma unroll
        for (int nt = 0; nt < 4; nt++) {
            acc[nt] = __builtin_amdgcn_mfma_f32_16x16x32_bf16(
                          a0, *(const short8*)&Bs[nt * 16 + c16][g * 8], acc[nt], 0, 0, 0);
            acc[nt] = __builtin_amdgcn_mfma_f32_16x16x32_bf16(
                          a1, *(const short8*)&Bs[nt * 16 + c16][32 + g * 8], acc[nt], 0, 0, 0);
        }
        __syncthreads();
    }

    const int crow = (lane >> 4) * 4, ccol = lane & 15;
    #pragma unroll
    for (int nt = 0; nt < 4; nt++) {
        const int n = n0 + nt * 16 + ccol;
        const float bv = bias ? bias[n] : 0.f;
        #pragma unroll
        for (int rr = 0; rr < 4; rr++) {
            const int m = m0 + wave * 16 + crow + rr;
            float v = acc[nt][rr] + bv;
            if (RELU) v = fmaxf(v, 0.f);
            stf(C + (size_t)m * N + n, v);
        }
    }
}

union Frag8 { bf16 h[8]; short8 v; };

// ============ single-sweep online-softmax MFMA attention ============
// itile remap: grid is (x=16 i-tiles, y=32 bh), x-major dispatch pairs block n with
// n+256 on the same CU with the SAME i-tile (256%16==0) -> per-CU work 2*(17..32).
// Pair long with short instead: itile = (by<16) ? bx : 15-bx  -> constant 49/CU.
__global__ __launch_bounds__(256)
void flash_attn_k(const float* __restrict__ q, const bf16* __restrict__ kv,
                  const bf16* __restrict__ rg, const float* __restrict__ ub,
                  const float* __restrict__ vb,
                  float* __restrict__ m_arr, float* __restrict__ l_arr,
                  bf16* __restrict__ vec)
{
    __shared__ alignas(16) bf16 Ks[64][72];
    __shared__ alignas(16) bf16 Rs[128][72];
    __shared__ alignas(16) bf16 BDs[64][136];
    bf16 (*Vt)[72] = (bf16 (*)[72])&Rs[0][0];     // V^T [d][j], aliases Rs

    const int itile = (blockIdx.y < (NBAT * NHEAD / 2))
                          ? blockIdx.x : (gridDim.x - 1 - blockIdx.x);
    const int i0 = itile * 64;
    const int bh = blockIdx.y;
    const int b = bh >> 4, h = bh & 15;
    const int tid = threadIdx.x;
    const int wave = tid >> 6, lane = tid & 63;
    const int g = lane >> 4, c16 = lane & 15;
    const int dib = wave * 16 + g * 4;

    Frag8 fu0, fu1, fv0, fv1;
    {
        const float* qrow = q + ((size_t)(i0 + wave * 16 + c16) * NBAT + b) * HDIM + h * DHEAD;
        const float* ubp = ub + h * DHEAD;
        const float* vbp = vb + h * DHEAD;
        #pragma unroll
        for (int e = 0; e < 8; e++) {
            float q0 = qrow[g * 8 + e], q1 = qrow[32 + g * 8 + e];
            fu0.h[e] = __float2bfloat16(q0 + ubp[g * 8 + e]);
            fu1.h[e] = __float2bfloat16(q1 + ubp[32 + g * 8 + e]);
            fv0.h[e] = __float2bfloat16(q0 + vbp[g * 8 + e]);
            fv1.h[e] = __float2bfloat16(q1 + vbp[32 + g * 8 + e]);
        }
    }

    float mrow[4] = {-3e38f, -3e38f, -3e38f, -3e38f};
    float lrow[4] = {0.f, 0.f, 0.f, 0.f};
    f32x4 Oacc[4];
    #pragma unroll
    for (int nt = 0; nt < 4; nt++) Oacc[nt] = (f32x4)(0.f);

    const int ntiles = i0 / 64 + 17;

    for (int t = 0; t < ntiles; t++) {
        const int j0 = t * 64;
        const int jj0 = j0 + (LQ - 64) - i0;
        {
            const int row = tid >> 2, dbase = (tid & 3) * 16;
            const bf16* src = kv + ((size_t)(j0 + row) * NBAT + b) * (2 * HDIM)
                                 + h * DHEAD + dbase;
            *(uint4*)&Ks[row][dbase]     = *(const uint4*)src;
            *(uint4*)&Ks[row][dbase + 8] = *(const uint4*)(src + 8);
        }
        {
            const int row = tid >> 1, dbase = (tid & 1) * 32;
            const int jj = jj0 + row;
            if (jj < TKEY) {
                const bf16* src = rg + ((size_t)jj * NBAT + b) * HDIM + h * DHEAD + dbase;
                #pragma unroll
                for (int u = 0; u < 4; u++)
                    *(uint4*)&Rs[row][dbase + u * 8] = *(const uint4*)(src + u * 8);
            } else {
                const uint4 z = make_uint4(0, 0, 0, 0);
                #pragma unroll
                for (int u = 0; u < 4; u++)
                    *(uint4*)&Rs[row][dbase + u * 8] = z;
            }
        }
        __syncthreads();
        f32x4 ac[4];
        #pragma unroll
        for (int nt = 0; nt < 4; nt++) {
            ac[nt] = (f32x4)(0.f);
            ac[nt] = __builtin_amdgcn_mfma_f32_16x16x32_bf16(
                         fu0.v, *(const short8*)&Ks[nt * 16 + c16][g * 8], ac[nt], 0, 0, 0);
            ac[nt] = __builtin_amdgcn_mfma_f32_16x16x32_bf16(
                         fu1.v, *(const short8*)&Ks[nt * 16 + c16][32 + g * 8], ac[nt], 0, 0, 0);
        }
        #pragma unroll
        for (int nt = 0; nt < 8; nt++) {
            f32x4 bd = (f32x4)(0.f);
            bd = __builtin_amdgcn_mfma_f32_16x16x32_bf16(
                     fv0.v, *(const short8*)&Rs[nt * 16 + c16][g * 8], bd, 0, 0, 0);
            bd = __builtin_amdgcn_mfma_f32_16x16x32_bf16(
                     fv1.v, *(const short8*)&Rs[nt * 16 + c16][32 + g * 8], bd, 0, 0, 0);
            #pragma unroll
            for (int reg = 0; reg < 4; reg++)
                BDs[dib + reg][nt * 16 + c16] = __float2bfloat16(bd[reg]);
        }
        __syncthreads();
        {
            const int j = tid & 63, dbase = (tid >> 6) * 16;
            const bf16* src = kv + ((size_t)(j0 + j) * NBAT + b) * (2 * HDIM)
                                 + HDIM + h * DHEAD + dbase;
            bf16 tmp[16];
            *(uint4*)&tmp[0] = *(const uint4*)src;
            *(uint4*)&tmp[8] = *(const uint4*)(src + 8);
            #pragma unroll
            for (int e = 0; e < 16; e++) Vt[dbase + e][j] = tmp[e];
        }
        float sv[4][4];
        #pragma unroll
        for (int reg = 0; reg < 4; reg++) {
            const int di = dib + reg;
            const int colbase = 63 - di;
            #pragma unroll
            for (int nt = 0; nt < 4; nt++) {
                const int dj = nt * 16 + c16;
                float s = (ac[nt][reg] +
                           __bfloat162float(BDs[di][colbase + dj])) * SCALE_F;
                if (j0 + dj > i0 + di + MEMLEN) s = -1e30f;
                sv[nt][reg] = s;
            }
        }
        #pragma unroll
        for (int reg = 0; reg < 4; reg++) {
            float tm = fmaxf(fmaxf(sv[0][reg], sv[1][reg]),
                             fmaxf(sv[2][reg], sv[3][reg]));
            #pragma unroll
            for (int mk = 1; mk < 16; mk <<= 1)
                tm = fmaxf(tm, __shfl_xor(tm, mk));
            const float nm = fmaxf(mrow[reg], tm);
            const float alpha = __expf(mrow[reg] - nm);
            float ev[4];
            #pragma unroll
            for (int nt = 0; nt < 4; nt++) ev[nt] = __expf(sv[nt][reg] - nm);
            float ps = ev[0] + ev[1] + ev[2] + ev[3];
            #pragma unroll
            for (int mk = 1; mk < 16; mk <<= 1)
                ps += __shfl_xor(ps, mk);
            lrow[reg] = lrow[reg] * alpha + ps;
            mrow[reg] = nm;
            #pragma unroll
            for (int nt = 0; nt < 4; nt++) {
                Oacc[nt][reg] *= alpha;
                BDs[dib + reg][nt * 16 + c16] = __float2bfloat16(ev[nt]);
            }
        }
        __syncthreads();
        short8 p0 = *(const short8*)&BDs[wave * 16 + c16][g * 8];
        short8 p1 = *(const short8*)&BDs[wave * 16 + c16][32 + g * 8];
        #pragma unroll
        for (int nt = 0; nt < 4; nt++) {
            Oacc[nt] = __builtin_amdgcn_mfma_f32_16x16x32_bf16(
                           p0, *(const short8*)&Vt[nt * 16 + c16][g * 8], Oacc[nt], 0, 0, 0);
            Oacc[nt] = __builtin_amdgcn_mfma_f32_16x16x32_bf16(
                           p1, *(const short8*)&Vt[nt * 16 + c16][32 + g * 8], Oacc[nt], 0, 0, 0);
        }
        __syncthreads();
    }

    float invl[4];
    #pragma unroll
    for (int reg = 0; reg < 4; reg++) invl[reg] = 1.f / lrow[reg];
    #pragma unroll
    for (int nt = 0; nt < 4; nt++)
        #pragma unroll
        for (int reg = 0; reg < 4; reg++)
            vec[((size_t)(i0 + dib + reg) * NBAT + b) * HDIM + h * DHEAD + nt * 16 + c16]
                = __float2bfloat16(Oacc[nt][reg] * invl[reg]);
    if (c16 == 0) {
        #pragma unroll
        for (int reg = 0; reg < 4; reg++) {
            const int idx = ((i0 + dib + reg) * NBAT + b) * NHEAD + h;
            m_arr[idx] = mrow[reg];
            l_arr[idx] = lrow[reg];
        }
    }
}

// ============ attn matrix via MFMA — balanced flattened grid + bh-split ============
// grid = (392 valid (i,j) tiles, 2 batch-halves of 16 bh). attnp must be zero-filled
// first; each half atomically adds its psum. 784 equal blocks -> ~3/CU, no tail.
__global__ __launch_bounds__(256)
void attn_mat4_k(const float* __restrict__ q, const bf16* __restrict__ kv,
                 const bf16* __restrict__ rg, const float* __restrict__ ub,
                 const float* __restrict__ vb, const float* __restrict__ m_arr,
                 const float* __restrict__ l_arr, float* __restrict__ attn)
{
    // decode flattened valid-tile index: i-tile it has it+17 valid j-tiles
    int f = blockIdx.x, it = 0, base = 0;
    for (it = 0; it < 16; it++) {
        const int cnt = it + 17;
        if (f < base + cnt) break;
        base += cnt;
    }
    const int i0 = it * 64;
    const int j0 = (f - base) * 64;
    const int bhb = blockIdx.y * 16;

    __shared__ alignas(16) bf16 Ks[64][72];
    __shared__ alignas(16) bf16 Rs[128][72];
    __shared__ alignas(16) bf16 BDs[64][136];
    const int tid = threadIdx.x;
    const int wave = tid >> 6, lane = tid & 63;
    const int g = lane >> 4, c16 = lane & 15;
    const int dib = wave * 16 + g * 4;
    const int jj0 = j0 + (LQ - 64) - i0;
    float psum[4][4] = {};

    for (int bh = bhb; bh < bhb + 16; bh++) {
        const int b = bh >> 4, h = bh & 15;
        Frag8 fu0, fu1, fv0, fv1;
        {
            const float* qrow = q + ((size_t)(i0 + wave * 16 + c16) * NBAT + b) * HDIM + h * DHEAD;
            const float* ubp = ub + h * DHEAD;
            const float* vbp = vb + h * DHEAD;
            #pragma unroll
            for (int e = 0; e < 8; e++) {
                float q0 = qrow[g * 8 + e], q1 = qrow[32 + g * 8 + e];
                fu0.h[e] = __float2bfloat16(q0 + ubp[g * 8 + e]);
                fu1.h[e] = __float2bfloat16(q1 + ubp[32 + g * 8 + e]);
                fv0.h[e] = __float2bfloat16(q0 + vbp[g * 8 + e]);
                fv1.h[e] = __float2bfloat16(q1 + vbp[32 + g * 8 + e]);
            }
        }
        {
            const int row = tid >> 2, dbase = (tid & 3) * 16;
            const bf16* src = kv + ((size_t)(j0 + row) * NBAT + b) * (2 * HDIM)
                                 + h * DHEAD + dbase;
            *(uint4*)&Ks[row][dbase]     = *(const uint4*)src;
            *(uint4*)&Ks[row][dbase + 8] = *(const uint4*)(src + 8);
        }
        {
            const int row = tid >> 1, dbase = (tid & 1) * 32;
            const int jj = jj0 + row;
            if (jj < TKEY) {
                const bf16* src = rg + ((size_t)jj * NBAT + b) * HDIM + h * DHEAD + dbase;
                #pragma unroll
                for (int u = 0; u < 4; u++)
                    *(uint4*)&Rs[row][dbase + u * 8] = *(const uint4*)(src + u * 8);
            } else {
                const uint4 z = make_uint4(0, 0, 0, 0);
                #pragma unroll
                for (int u = 0; u < 4; u++)
                    *(uint4*)&Rs[row][dbase + u * 8] = z;
            }
        }
        __syncthreads();
        f32x4 ac[4];
        #pragma unroll
        for (int nt = 0; nt < 4; nt++) {
            ac[nt] = (f32x4)(0.f);
            ac[nt] = __builtin_amdgcn_mfma_f32_16x16x32_bf16(
                         fu0.v, *(const short8*)&Ks[nt * 16 + c16][g * 8], ac[nt], 0, 0, 0);
            ac[nt] = __builtin_amdgcn_mfma_f32_16x16x32_bf16(
                         fu1.v, *(const short8*)&Ks[nt * 16 + c16][32 + g * 8], ac[nt], 0, 0, 0);
        }
        #pragma unroll
        for (int nt = 0; nt < 8; nt++) {
            f32x4 bd = (f32x4)(0.f);
            bd = __builtin_amdgcn_mfma_f32_16x16x32_bf16(
                     fv0.v, *(const short8*)&Rs[nt * 16 + c16][g * 8], bd, 0, 0, 0);
            bd = __builtin_amdgcn_mfma_f32_16x16x32_bf16(
                     fv1.v, *(const short8*)&Rs[nt * 16 + c16][32 + g * 8], bd, 0, 0, 0);
            #pragma unroll
            for (int reg = 0; reg < 4; reg++)
                BDs[dib + reg][nt * 16 + c16] = __float2bfloat16(bd[reg]);
        }
        #pragma unroll
        for (int reg = 0; reg < 4; reg++) {
            const int di = dib + reg;
            const int colbase = 63 - di;
            const int idx = ((i0 + di) * NBAT + b) * NHEAD + h;
            const float mi = m_arr[idx];
            const float il = 1.f / l_arr[idx];
            #pragma unroll
            for (int nt = 0; nt < 4; nt++) {
                const int dj = nt * 16 + c16;
                float s = (ac[nt][reg] +
                           __bfloat162float(BDs[di][colbase + dj])) * SCALE_F;
                float p = (j0 + dj > i0 + di + MEMLEN) ? 0.f : __expf(s - mi) * il;
                psum[nt][reg] += p;
            }
        }
        __syncthreads();
    }
    const float inv = 1.f / (NBAT * NHEAD);
    #pragma unroll
    for (int nt = 0; nt < 4; nt++)
        #pragma unroll
        for (int reg = 0; reg < 4; reg++)
            atomicAdd(&attn[(size_t)(i0 + dib + reg) * TKEY + j0 + nt * 16 + c16],
                      psum[nt][reg] * inv);
}

// ---------------- fused residual + LayerNorm ----------------
template<typename T1, typename T2, typename TOUT>
__global__ __launch_bounds__(256)
void ln_k(const T1* __restrict__ a, const T2* __restrict__ c,
          const float* __restrict__ g, const float* __restrict__ bb,
          TOUT* __restrict__ out)
{
    const int row = blockIdx.x;
    const int tid = threadIdx.x;
    const size_t base = (size_t)row * DMOD;
    float vals[4];
    float s = 0.f, sq = 0.f;
    #pragma unroll
    for (int t = 0; t < 4; t++) {
        const int dcol = tid + t * 256;
        float v = ldf(a + base + dcol) + ldf(c + base + dcol);
        vals[t] = v; s += v; sq += v * v;
    }
    __shared__ float rs[256], rq[256];
    rs[tid] = s; rq[tid] = sq;
    __syncthreads();
    for (int st = 128; st > 0; st >>= 1) {
        if (tid < st) { rs[tid] += rs[tid + st]; rq[tid] += rq[tid + st]; }
        __syncthreads();
    }
    const float mean = rs[0] / DMOD;
    const float var = rq[0] / DMOD - mean * mean;
    const float rstd = rsqrtf(fmaxf(var, 0.f) + EPS_F);
    #pragma unroll
    for (int t = 0; t < 4; t++) {
        const int dcol = tid + t * 256;
        float v = (vals[t] - mean) * rstd * g[dcol] + bb[dcol];
        stf(out + base + dcol, v);
    }
}

// ---------------- residual + NP split-K fp32 partials (+optional bias) + LayerNorm ----
template<typename TA, int NP, bool HASB, typename TOUT>
__global__ __launch_bounds__(256)
void lnp_k(const TA* __restrict__ a, const float* __restrict__ part, size_t pstride,
           const float* __restrict__ biasvec, const float* __restrict__ g,
           const float* __restrict__ bb, TOUT* __restrict__ out)
{
    const int row = blockIdx.x;
    const int tid = threadIdx.x;
    const size_t base = (size_t)row * DMOD;
    float vals[4];
    float s = 0.f, sq = 0.f;
    #pragma unroll
    for (int t = 0; t < 4; t++) {
        const int dcol = tid + t * 256;
        float v = ldf(a + base + dcol);
        #pragma unroll
        for (int p = 0; p < NP; p++) v += part[(size_t)p * pstride + base + dcol];
        if (HASB) v += biasvec[dcol];
        vals[t] = v; s += v; sq += v * v;
    }
    __shared__ float rs[256], rq[256];
    rs[tid] = s; rq[tid] = sq;
    __syncthreads();
    for (int st = 128; st > 0; st >>= 1) {
        if (tid < st) { rs[tid] += rs[tid + st]; rq[tid] += rq[tid + st]; }
        __syncthreads();
    }
    const float mean = rs[0] / DMOD;
    const float var = rq[0] / DMOD - mean * mean;
    const float rstd = rsqrtf(fmaxf(var, 0.f) + EPS_F);
    #pragma unroll
    for (int t = 0; t < 4; t++) {
        const int dcol = tid + t * 256;
        float v = (vals[t] - mean) * rstd * g[dcol] + bb[dcol];
        stf(out + base + dcol, v);
    }
}

__global__ void fill_zero_k(float* __restrict__ p, int n) {
    int i = blockIdx.x * 256 + threadIdx.x;
    if (i < n) p[i] = 0.f;
}

extern "C" void kernel_launch(void* const* d_in, const int* in_sizes, int n_in,
                              void* d_out, int out_size, void* d_ws, size_t ws_size,
                              hipStream_t stream)
{
    const float* x    = (const float*)d_in[0];
    const float* pos  = (const float*)d_in[1];
    const float* ub   = (const float*)d_in[2];
    const float* vb   = (const float*)d_in[3];
    const float* memp = (const float*)d_in[4];
    const float* Wq   = (const float*)d_in[5];
    const float* Wkv  = (const float*)d_in[6];
    const float* Wo   = (const float*)d_in[7];
    const float* Wrel = (const float*)d_in[8];
    const float* ln1g = (const float*)d_in[9];
    const float* ln1b = (const float*)d_in[10];
    const float* W1   = (const float*)d_in[11];
    const float* b1   = (const float*)d_in[12];
    const float* W2   = (const float*)d_in[13];
    const float* b2   = (const float*)d_in[14];
    const float* ln2g = (const float*)d_in[15];
    const float* ln2b = (const float*)d_in[16];
    // d_in[17] = mask: analytic (j > i + MEM), unused

    // ---- workspace, lifetime-aliased ----
    char* wsb = (char*)d_ws;
    const size_t MB = 1048576;
    bf16*  kvb   = (bf16*)(wsb + 0);          // [T*B][2H] attention phases
    bf16*  h1    = (bf16*)(wsb + 0);          // [L*B][DFF] FF phase
    bf16*  rb    = (bf16*)(wsb + 16 * MB);    // [T*B][H]  attention phases
    bf16*  aout  = (bf16*)(wsb + 16 * MB);    // [L*B][D]  (fallback path only)
    bf16*  f2o   = (bf16*)(wsb + 16 * MB);    // [L*B][D]  (fallback path only)
    bf16*  out1  = (bf16*)(wsb + 20 * MB);    // [L*B][D]
    bf16*  vecb  = (bf16*)(wsb + 24 * MB);    // [L*B][H]
    float* m_arr = (float*)(wsb + 28 * MB);
    float* l_arr = (float*)(wsb + 28 * MB + 131072);
    const size_t ws_need_old = 28 * MB + 262144;
    // fast-path extras
    bf16*  catc  = (bf16*)(wsb + 30 * MB);    // [T*B][D] concat bf16, 8MB (dead after q GEMM)
    bf16*  posc  = (bf16*)(wsb + 38 * MB);    // [T*B][D] pos bf16, 8MB (dead after r GEMM)
    float* part2 = (float*)(wsb + 30 * MB);   // 2x [L*B][D] fp32 split-K partials, 16MB
    bf16*  wscr  = (bf16*)(wsb + 46 * MB);    // weight scratch, 8MB (4M bf16 elems)
    const size_t ws_need_new = 54 * MB;

    float* outp  = (float*)d_out;
    float* attnp = outp + (size_t)LQ * NBAT * DMOD;
    float* qb    = outp;                      // q scratch (dead before final LN)

    const dim3 blk(256);
    const size_t PSTRIDE = (size_t)LQ * NBAT * DMOD;   // partial slice stride (elems)
    const int NATTN = LQ * TKEY;                       // attn matrix elems

    if (ws_size < ws_need_old) {
        fill_zero_k<<<dim3((out_size + 255) / 256), blk, 0, stream>>>(outp, out_size);
        return;
    }

    if (ws_size >= ws_need_new) {
        // ======== fast path ========
        const int nCat = MEMLEN * NBAT * DMOD;      // 2M elems
        const int nPos = TKEY * NBAT * DMOD;        // 4M elems
        // one fused convert launch: mem->catc, x->catc+2M, pos->posc
        cvt3_bf16_k<<<dim3((2 * nCat + nPos) / 2048), blk, 0, stream>>>(
            memp, catc, nCat, x, catc + (size_t)nCat, nCat, pos, posc, nPos);
        // one fused weight transpose launch: Wkv->wscr, Wrel->wscr+2M, Wq->wscr+3M
        tcvt3_k<<<dim3(1024), blk, 0, stream>>>(
            Wkv, wscr, Wrel, wscr + (size_t)2 * MB, Wq, wscr + (size_t)3 * MB);

        // kv = cat @ Wkv -> bf16 [4096 x 2048]
        mgemm128_k<1, false, bf16><<<dim3(2 * HDIM / 128, TKEY * NBAT / 128, 1), blk, 0, stream>>>(
            catc, wscr, nullptr, kvb, TKEY * NBAT, 2 * HDIM, DMOD);
        // r = pos @ Wrel -> bf16 [4096 x 1024]
        mgemm128_k<1, false, bf16><<<dim3(HDIM / 128, TKEY * NBAT / 128, 1), blk, 0, stream>>>(
            posc, wscr + (size_t)2 * MB, nullptr, rb, TKEY * NBAT, HDIM, DMOD);
        // q = x @ Wq -> fp32 [2048 x 1024]
        mgemm128_k<1, false, float><<<dim3(HDIM / 128, LQ * NBAT / 128, 1), blk, 0, stream>>>(
            catc + (size_t)nCat, wscr + (size_t)3 * MB, nullptr, qb, LQ * NBAT, HDIM, DMOD);

        // zero attn matrix (attn_mat4 accumulates atomically)
        fill_zero_k<<<dim3((NATTN + 255) / 256), blk, 0, stream>>>(attnp, NATTN);

        flash_attn_k<<<dim3(LQ / 64, NBAT * NHEAD), blk, 0, stream>>>(
            qb, kvb, rb, ub, vb, m_arr, l_arr, vecb);
        attn_mat4_k<<<dim3(392, 2), blk, 0, stream>>>(
            qb, kvb, rb, ub, vb, m_arr, l_arr, attnp);

        // attn_out = vec @ Wo : split-K=2 fp32 partials (catc/posc dead now)
        tcvt_bf16_k<<<dim3(DMOD / 64, HDIM / 64), blk, 0, stream>>>(Wo, wscr, HDIM, DMOD);
        mgemm128_k<2, false, float><<<dim3(DMOD / 128, LQ * NBAT / 128, 2), blk, 0, stream>>>(
            vecb, wscr, nullptr, part2, LQ * NBAT, DMOD, HDIM);
        // out1 = LN(x + p0 + p1)
        lnp_k<float, 2, false, bf16><<<dim3(LQ * NBAT), blk, 0, stream>>>(
            x, part2, PSTRIDE, nullptr, ln1g, ln1b, out1);
        // h1 = relu(out1 @ W1 + b1)
        tcvt_bf16_k<<<dim3(DFFN / 64, DMOD / 64), blk, 0, stream>>>(W1, wscr, DMOD, DFFN);
        mgemm128_k<1, true, bf16><<<dim3(DFFN / 128, LQ * NBAT / 128, 1), blk, 0, stream>>>(
            out1, wscr, b1, h1, LQ * NBAT, DFFN, DMOD);
        // ff partials = h1 @ W2 : split-K=2
        tcvt_bf16_k<<<dim3(DMOD / 64, DFFN / 64), blk, 0, stream>>>(W2, wscr, DFFN, DMOD);
        mgemm128_k<2, false, float><<<dim3(DMOD / 128, LQ * NBAT / 128, 2), blk, 0, stream>>>(
            h1, wscr, nullptr, part2, LQ * NBAT, DMOD, DFFN);
        // out = LN(out1 + p0 + p1 + b2)
        lnp_k<bf16, 2, true, float><<<dim3(LQ * NBAT), blk, 0, stream>>>(
            out1, part2, PSTRIDE, b2, ln2g, ln2b, outp);
        return;
    }

    // ======== fallback path ========
    mgemm64_k<float, bf16, false><<<dim3(2 * HDIM / 64, TKEY * NBAT / 64), blk, 0, stream>>>(
        memp, x, MEMLEN * NBAT, Wkv, nullptr, kvb, TKEY * NBAT, 2 * HDIM, DMOD);
    mgemm64_k<float, bf16, false><<<dim3(HDIM / 64, TKEY * NBAT / 64), blk, 0, stream>>>(
        pos, pos, TKEY * NBAT, Wrel, nullptr, rb, TKEY * NBAT, HDIM, DMOD);
    mgemm64_k<float, float, false><<<dim3(HDIM / 64, LQ * NBAT / 64), blk, 0, stream>>>(
        x, x, LQ * NBAT, Wq, nullptr, qb, LQ * NBAT, HDIM, DMOD);

    fill_zero_k<<<dim3((NATTN + 255) / 256), blk, 0, stream>>>(attnp, NATTN);
    flash_attn_k<<<dim3(LQ / 64, NBAT * NHEAD), blk, 0, stream>>>(
        qb, kvb, rb, ub, vb, m_arr, l_arr, vecb);
    attn_mat4_k<<<dim3(392, 2), blk, 0, stream>>>(
        qb, kvb, rb, ub, vb, m_arr, l_arr, attnp);

    mgemm64_k<bf16, bf16, false><<<dim3(DMOD / 64, LQ * NBAT / 64), blk, 0, stream>>>(
        vecb, vecb, LQ * NBAT, Wo, nullptr, aout, LQ * NBAT, DMOD, HDIM);
    ln_k<float, bf16, bf16><<<dim3(LQ * NBAT), blk, 0, stream>>>(x, aout, ln1g, ln1b, out1);
    mgemm64_k<bf16, bf16, true><<<dim3(DFFN / 64, LQ * NBAT / 64), blk, 0, stream>>>(
        out1, out1, LQ * NBAT, W1, b1, h1, LQ * NBAT, DFFN, DMOD);
    mgemm64_k<bf16, bf16, false><<<dim3(DMOD / 64, LQ * NBAT / 64), blk, 0, stream>>>(
        h1, h1, LQ * NBAT, W2, b2, f2o, LQ * NBAT, DMOD, DFFN);
    ln_k<bf16, bf16, float><<<dim3(LQ * NBAT), blk, 0, stream>>>(out1, f2o, ln2g, ln2b, outp);
}

// Round 5
// 543.393 us; speedup vs baseline: 1.2024x; 1.0480x over previous
//
#include <hip/hip_runtime.h>
#include <hip/hip_bf16.h>

using bf16 = __hip_bfloat16;

#define LQ      1024
#define NBAT    2
#define DMOD    1024
#define NHEAD   16
#define DHEAD   64
#define DFFN    4096
#define MEMLEN  1024
#define TKEY    2048
#define HDIM    1024
#define SCALE_F 0.125f
#define EPS_F   1e-5f

typedef __attribute__((ext_vector_type(8))) short short8;
typedef __attribute__((ext_vector_type(4))) float f32x4;

__device__ __forceinline__ float ldf(const float* p) { return *p; }
__device__ __forceinline__ float ldf(const bf16* p) { return __bfloat162float(*p); }
__device__ __forceinline__ void stf(float* p, float v) { *p = v; }
__device__ __forceinline__ void stf(bf16* p, float v) { *p = __float2bfloat16(v); }

// copy 4 elements (converting to bf16) into LDS, 8B store
__device__ __forceinline__ void cpy4(bf16* dst, const float* src) {
    float4 w = *(const float4*)src;
    bf16 t[4] = {__float2bfloat16(w.x), __float2bfloat16(w.y),
                 __float2bfloat16(w.z), __float2bfloat16(w.w)};
    *(uint2*)dst = *(uint2*)t;
}
__device__ __forceinline__ void cpy4(bf16* dst, const bf16* src) {
    *(uint2*)dst = *(const uint2*)src;
}

// async global->LDS 16B: LDS dest is wave-uniform base + lane*16
__device__ __forceinline__ void gload_lds16(const bf16* g, bf16* l) {
    __builtin_amdgcn_global_load_lds(
        (const __attribute__((address_space(1))) unsigned int*)g,
        (__attribute__((address_space(3))) unsigned int*)l, 16, 0, 0);
}

// T2 swizzle: logical (row, colE) -> LDS elem index. 8-elem (16B) granular XOR of
// row&7 spreads the 128B-stride column reads across 8 slots (2-way = free).
#define SWZ(row, colE) ((row) * 64 + ((colE) ^ (((row) & 7) << 3)))

// ---------------- fused fp32 -> bf16 elementwise converts (3 ranges, 1 launch) -------
__global__ __launch_bounds__(256)
void cvt3_bf16_k(const float* __restrict__ s0, bf16* __restrict__ d0, int n0,
                 const float* __restrict__ s1, bf16* __restrict__ d1, int n1,
                 const float* __restrict__ s2, bf16* __restrict__ d2, int n2)
{
    int i = (blockIdx.x * 256 + threadIdx.x) * 8;
    const float* s; bf16* d;
    if (i < n0)           { s = s0; d = d0; }
    else if (i < n0 + n1) { s = s1; d = d1; i -= n0; }
    else if (i < n0 + n1 + n2) { s = s2; d = d2; i -= n0 + n1; }
    else return;
    float4 v0 = *(const float4*)(s + i);
    float4 v1 = *(const float4*)(s + i + 4);
    bf16 t[8] = {__float2bfloat16(v0.x), __float2bfloat16(v0.y),
                 __float2bfloat16(v0.z), __float2bfloat16(v0.w),
                 __float2bfloat16(v1.x), __float2bfloat16(v1.y),
                 __float2bfloat16(v1.z), __float2bfloat16(v1.w)};
    *(uint4*)(d + i) = *(uint4*)t;
}

// ---------------- W [K][N] fp32 -> Wt [N][K] bf16, 64x64 tile body ----------------
__device__ __forceinline__ void tcvt_tile(const float* __restrict__ W,
                                          bf16* __restrict__ Wt,
                                          int K, int N, int n0, int k0, int tid,
                                          bf16 (*tile)[65])
{
    const int r = tid >> 2, cb = (tid & 3) * 16;
    #pragma unroll
    for (int e = 0; e < 16; e++)
        tile[r][cb + e] = __float2bfloat16(W[(size_t)(k0 + r) * N + n0 + cb + e]);
    __syncthreads();
    bf16 t[16];
    #pragma unroll
    for (int e = 0; e < 16; e++) t[e] = tile[cb + e][r];
    bf16* dst = Wt + (size_t)(n0 + r) * K + k0 + cb;
    *(uint4*)dst       = ((uint4*)t)[0];
    *(uint4*)(dst + 8) = ((uint4*)t)[1];
}

__global__ __launch_bounds__(256)
void tcvt_bf16_k(const float* __restrict__ W, bf16* __restrict__ Wt, int K, int N)
{
    __shared__ alignas(16) bf16 tile[64][65];
    tcvt_tile(W, Wt, K, N, blockIdx.x * 64, blockIdx.y * 64, threadIdx.x, tile);
}

// batched transpose-convert: Wkv(1024x2048) + Wrel(1024x1024) + Wq(1024x1024), K=1024
__global__ __launch_bounds__(256)
void tcvt3_k(const float* __restrict__ Wkv_, bf16* __restrict__ dkv,
             const float* __restrict__ Wrel_, bf16* __restrict__ dr,
             const float* __restrict__ Wq_, bf16* __restrict__ dq)
{
    __shared__ alignas(16) bf16 tile[64][65];
    int bid = blockIdx.x;
    const float* W; bf16* Wt; int N;
    if (bid < 512)      { W = Wkv_;  Wt = dkv; N = 2048; }
    else if (bid < 768) { W = Wrel_; Wt = dr;  N = 1024; bid -= 512; }
    else                { W = Wq_;   Wt = dq;  N = 1024; bid -= 768; }
    const int nb = N / 64;
    tcvt_tile(W, Wt, DMOD, N, (bid % nb) * 64, (bid / nb) * 64, threadIdx.x, tile);
}

// ---------------- MFMA GEMM, 128x128 tile, BK=64, dbuf + T2 LDS swizzle -------------
// A [M][K] bf16 row-major, Bt [N][K] bf16 row-major (pre-transposed weights).
// 256 threads = 4 waves in 2x2; each wave computes a 64x64 output sub-tile.
// LDS layout swizzled (SWZ): global_load_lds writes linearly, so the per-lane GLOBAL
// source column is pre-permuted (cc = ((lane&7)^(lane>>3))*8) and ds_reads apply the
// same XOR -> 16-lane column reads spread over 8 slots (2-way, conflict-free).
// SPLITS>1: blockIdx.z selects a K-slice; fp32 partials to Cbase + z*M*N (no bias).
template<int SPLITS, bool RELU, typename TOUT>
__global__ __launch_bounds__(256)
void mgemm128_k(const bf16* __restrict__ A, const bf16* __restrict__ Bt,
                const float* __restrict__ bias, TOUT* __restrict__ Cbase,
                int M, int N, int K)
{
    __shared__ alignas(16) bf16 As[2][128 * 64];
    __shared__ alignas(16) bf16 Bs[2][128 * 64];
    const int tid  = threadIdx.x;
    const int wave = tid >> 6, lane = tid & 63;
    const int m0 = blockIdx.y * 128, n0 = blockIdx.x * 128;
    const int g = lane >> 4, c16 = lane & 15;
    const int wr = (wave >> 1) * 64, wc = (wave & 1) * 64;

    const int klen   = K / SPLITS;
    const int kstart = blockIdx.z * klen;
    TOUT* C = Cbase + (size_t)blockIdx.z * M * N;

    f32x4 acc[4][4];
    #pragma unroll
    for (int mi = 0; mi < 4; mi++)
        #pragma unroll
        for (int ni = 0; ni < 4; ni++) acc[mi][ni] = (f32x4)(0.f);

    // staging map: wave w issue q covers rows 32w + 8q + (lane>>3);
    // source k-col permuted to realize the SWZ layout under linear LDS-DMA writes
    const int r0 = (wave << 5) + (lane >> 3);
    const int cc = (((lane & 7) ^ (lane >> 3)) << 3);
    const bf16* agp = A  + (size_t)(m0 + r0) * K + kstart + cc;
    const bf16* bgp = Bt + (size_t)(n0 + r0) * K + kstart + cc;
    const int lb = wave * 2048;

    // prologue: stage K-step 0 into buffer 0
    #pragma unroll
    for (int q = 0; q < 4; q++) {
        gload_lds16(agp + (size_t)(q * 8) * K, &As[0][lb + q * 512]);
        gload_lds16(bgp + (size_t)(q * 8) * K, &Bs[0][lb + q * 512]);
    }

    int cur = 0;
    for (int k0 = 0; k0 < klen; k0 += 64) {
        if (k0 + 64 < klen) {   // issue next tile; stays in flight across barriers
            #pragma unroll
            for (int q = 0; q < 4; q++) {
                gload_lds16(agp + k0 + 64 + (size_t)(q * 8) * K, &As[cur ^ 1][lb + q * 512]);
                gload_lds16(bgp + k0 + 64 + (size_t)(q * 8) * K, &Bs[cur ^ 1][lb + q * 512]);
            }
            asm volatile("s_waitcnt vmcnt(8)" ::: "memory");
        } else {
            asm volatile("s_waitcnt vmcnt(0)" ::: "memory");
        }
        __builtin_amdgcn_s_barrier();          // cur buffer ready on all waves
        short8 af[4][2], bfr[4][2];
        #pragma unroll
        for (int mi = 0; mi < 4; mi++) {
            const int row = wr + mi * 16 + c16;
            af[mi][0] = *(const short8*)&As[cur][SWZ(row, g * 8)];
            af[mi][1] = *(const short8*)&As[cur][SWZ(row, 32 + g * 8)];
        }
        #pragma unroll
        for (int ni = 0; ni < 4; ni++) {
            const int row = wc + ni * 16 + c16;
            bfr[ni][0] = *(const short8*)&Bs[cur][SWZ(row, g * 8)];
            bfr[ni][1] = *(const short8*)&Bs[cur][SWZ(row, 32 + g * 8)];
        }
        #pragma unroll
        for (int mi = 0; mi < 4; mi++)
            #pragma unroll
            for (int ni = 0; ni < 4; ni++) {
                acc[mi][ni] = __builtin_amdgcn_mfma_f32_16x16x32_bf16(
                                  af[mi][0], bfr[ni][0], acc[mi][ni], 0, 0, 0);
                acc[mi][ni] = __builtin_amdgcn_mfma_f32_16x16x32_bf16(
                                  af[mi][1], bfr[ni][1], acc[mi][ni], 0, 0, 0);
            }
        __builtin_amdgcn_s_barrier();          // all waves done reading cur
        cur ^= 1;
    }

    // epilogue: C/D layout col=lane&15, row=(lane>>4)*4+reg
    const int crow = g * 4;
    #pragma unroll
    for (int ni = 0; ni < 4; ni++) {
        const int n = n0 + wc + ni * 16 + c16;
        const float bv = (SPLITS == 1 && bias) ? bias[n] : 0.f;
        #pragma unroll
        for (int mi = 0; mi < 4; mi++) {
            #pragma unroll
            for (int reg = 0; reg < 4; reg++) {
                const int m = m0 + wr + mi * 16 + crow + reg;
                float v = acc[mi][ni][reg] + bv;
                if (RELU) v = fmaxf(v, 0.f);
                stf(C + (size_t)m * N + n, v);
            }
        }
    }
}

// ---------------- MFMA GEMM, 64x64 tile (fallback path, fp32 weights) ----------------
template<typename TA, typename TOUT, bool RELU>
__global__ __launch_bounds__(256)
void mgemm64_k(const TA* __restrict__ A0, const TA* __restrict__ A1, int rowsplit,
               const float* __restrict__ Bw, const float* __restrict__ bias,
               TOUT* __restrict__ C, int M, int N, int K)
{
    __shared__ alignas(16) bf16 As[64][72];
    __shared__ alignas(16) bf16 Bs[64][72];
    const int tid  = threadIdx.x;
    const int m0   = blockIdx.y * 64;
    const int n0   = blockIdx.x * 64;
    const int wave = tid >> 6, lane = tid & 63;
    const int g = lane >> 4, c16 = lane & 15;

    f32x4 acc[4];
    #pragma unroll
    for (int nt = 0; nt < 4; nt++) acc[nt] = (f32x4)(0.f);

    const int ar = tid >> 2, akc = (tid & 3) * 16;
    const int grow = m0 + ar;
    const TA* Arow = (grow < rowsplit) ? (A0 + (size_t)grow * K)
                                       : (A1 + (size_t)(grow - rowsplit) * K);
    const int bn = tid & 63, bkb = (tid >> 6) * 16;
    const float* Bcol = Bw + n0 + bn;

    for (int k0 = 0; k0 < K; k0 += 64) {
        cpy4(&As[ar][akc],      Arow + k0 + akc);
        cpy4(&As[ar][akc + 4],  Arow + k0 + akc + 4);
        cpy4(&As[ar][akc + 8],  Arow + k0 + akc + 8);
        cpy4(&As[ar][akc + 12], Arow + k0 + akc + 12);
        {
            bf16 t16[16];
            #pragma unroll
            for (int e = 0; e < 16; e++)
                t16[e] = __float2bfloat16(Bcol[(size_t)(k0 + bkb + e) * N]);
            *(uint4*)&Bs[bn][bkb]     = *(uint4*)&t16[0];
            *(uint4*)&Bs[bn][bkb + 8] = *(uint4*)&t16[8];
        }
        __syncthreads();
        const short8 a0 = *(const short8*)&As[wave * 16 + c16][g * 8];
        const short8 a1 = *(const short8*)&As[wave * 16 + c16][32 + g * 8];
        #pragma unroll
        for (int nt = 0; nt < 4; nt++) {
            acc[nt] = __builtin_amdgcn_mfma_f32_16x16x32_bf16(
                          a0, *(const short8*)&Bs[nt * 16 + c16][g * 8], acc[nt], 0, 0, 0);
            acc[nt] = __builtin_amdgcn_mfma_f32_16x16x32_bf16(
                          a1, *(const short8*)&Bs[nt * 16 + c16][32 + g * 8], acc[nt], 0, 0, 0);
        }
        __syncthreads();
    }

    const int crow = (lane >> 4) * 4, ccol = lane & 15;
    #pragma unroll
    for (int nt = 0; nt < 4; nt++) {
        const int n = n0 + nt * 16 + ccol;
        const float bv = bias ? bias[n] : 0.f;
        #pragma unroll
        for (int rr = 0; rr < 4; rr++) {
            const int m = m0 + wave * 16 + crow + rr;
            float v = acc[nt][rr] + bv;
            if (RELU) v = fmaxf(v, 0.f);
            stf(C + (size_t)m * N + n, v);
        }
    }
}

union Frag8 { bf16 h[8]; short8 v; };

// ============ single-sweep online-softmax MFMA attention (2 barriers/tile) ============
// Vt now has its OWN buffer (no Rs alias): V stages in phase 1 with K/R, and the two
// mid-tile barriers are removed. BD-write->sv-read and P-write->PV-read are intra-wave
// stripe round-trips (rows dib..dib+15 = wave's stripe), ordered by the compiler's
// lgkmcnt waits -- no cross-wave hazard. Remaining barriers: after staging (cross-wave
// K/R/V visibility) and at loop end (protect buffers from next-tile staging).
__global__ __launch_bounds__(256)
void flash_attn_k(const float* __restrict__ q, const bf16* __restrict__ kv,
                  const bf16* __restrict__ rg, const float* __restrict__ ub,
                  const float* __restrict__ vb,
                  float* __restrict__ m_arr, float* __restrict__ l_arr,
                  bf16* __restrict__ vec)
{
    __shared__ alignas(16) bf16 Ks[64][72];
    __shared__ alignas(16) bf16 Rs[128][72];
    __shared__ alignas(16) bf16 Vt[64][72];       // V^T [d][j], separate buffer
    __shared__ alignas(16) bf16 BDs[64][136];

    const int itile = (blockIdx.y < (NBAT * NHEAD / 2))
                          ? blockIdx.x : (gridDim.x - 1 - blockIdx.x);
    const int i0 = itile * 64;
    const int bh = blockIdx.y;
    const int b = bh >> 4, h = bh & 15;
    const int tid = threadIdx.x;
    const int wave = tid >> 6, lane = tid & 63;
    const int g = lane >> 4, c16 = lane & 15;
    const int dib = wave * 16 + g * 4;

    Frag8 fu0, fu1, fv0, fv1;
    {
        const float* qrow = q + ((size_t)(i0 + wave * 16 + c16) * NBAT + b) * HDIM + h * DHEAD;
        const float* ubp = ub + h * DHEAD;
        const float* vbp = vb + h * DHEAD;
        #pragma unroll
        for (int e = 0; e < 8; e++) {
            float q0 = qrow[g * 8 + e], q1 = qrow[32 + g * 8 + e];
            fu0.h[e] = __float2bfloat16(q0 + ubp[g * 8 + e]);
            fu1.h[e] = __float2bfloat16(q1 + ubp[32 + g * 8 + e]);
            fv0.h[e] = __float2bfloat16(q0 + vbp[g * 8 + e]);
            fv1.h[e] = __float2bfloat16(q1 + vbp[32 + g * 8 + e]);
        }
    }

    float mrow[4] = {-3e38f, -3e38f, -3e38f, -3e38f};
    float lrow[4] = {0.f, 0.f, 0.f, 0.f};
    f32x4 Oacc[4];
    #pragma unroll
    for (int nt = 0; nt < 4; nt++) Oacc[nt] = (f32x4)(0.f);

    const int ntiles = i0 / 64 + 17;

    for (int t = 0; t < ntiles; t++) {
        const int j0 = t * 64;
        const int jj0 = j0 + (LQ - 64) - i0;
        // ---- phase 1: stage K, R, V (V to its own buffer now) ----
        {
            const int row = tid >> 2, dbase = (tid & 3) * 16;
            const bf16* src = kv + ((size_t)(j0 + row) * NBAT + b) * (2 * HDIM)
                                 + h * DHEAD + dbase;
            *(uint4*)&Ks[row][dbase]     = *(const uint4*)src;
            *(uint4*)&Ks[row][dbase + 8] = *(const uint4*)(src + 8);
        }
        {
            const int row = tid >> 1, dbase = (tid & 1) * 32;
            const int jj = jj0 + row;
            if (jj < TKEY) {
                const bf16* src = rg + ((size_t)jj * NBAT + b) * HDIM + h * DHEAD + dbase;
                #pragma unroll
                for (int u = 0; u < 4; u++)
                    *(uint4*)&Rs[row][dbase + u * 8] = *(const uint4*)(src + u * 8);
            } else {
                const uint4 z = make_uint4(0, 0, 0, 0);
                #pragma unroll
                for (int u = 0; u < 4; u++)
                    *(uint4*)&Rs[row][dbase + u * 8] = z;
            }
        }
        {
            const int j = tid & 63, dbase = (tid >> 6) * 16;
            const bf16* src = kv + ((size_t)(j0 + j) * NBAT + b) * (2 * HDIM)
                                 + HDIM + h * DHEAD + dbase;
            bf16 tmp[16];
            *(uint4*)&tmp[0] = *(const uint4*)src;
            *(uint4*)&tmp[8] = *(const uint4*)(src + 8);
            #pragma unroll
            for (int e = 0; e < 16; e++) Vt[dbase + e][j] = tmp[e];
        }
        __syncthreads();                           // staging visible to all waves
        // ---- QK^T (AC) ----
        f32x4 ac[4];
        #pragma unroll
        for (int nt = 0; nt < 4; nt++) {
            ac[nt] = (f32x4)(0.f);
            ac[nt] = __builtin_amdgcn_mfma_f32_16x16x32_bf16(
                         fu0.v, *(const short8*)&Ks[nt * 16 + c16][g * 8], ac[nt], 0, 0, 0);
            ac[nt] = __builtin_amdgcn_mfma_f32_16x16x32_bf16(
                         fu1.v, *(const short8*)&Ks[nt * 16 + c16][32 + g * 8], ac[nt], 0, 0, 0);
        }
        // ---- BD (rel) -> BDs stripe (intra-wave round-trip, no barrier) ----
        #pragma unroll
        for (int nt = 0; nt < 8; nt++) {
            f32x4 bd = (f32x4)(0.f);
            bd = __builtin_amdgcn_mfma_f32_16x16x32_bf16(
                     fv0.v, *(const short8*)&Rs[nt * 16 + c16][g * 8], bd, 0, 0, 0);
            bd = __builtin_amdgcn_mfma_f32_16x16x32_bf16(
                     fv1.v, *(const short8*)&Rs[nt * 16 + c16][32 + g * 8], bd, 0, 0, 0);
            #pragma unroll
            for (int reg = 0; reg < 4; reg++)
                BDs[dib + reg][nt * 16 + c16] = __float2bfloat16(bd[reg]);
        }
        // ---- scores + online softmax ----
        float sv[4][4];
        #pragma unroll
        for (int reg = 0; reg < 4; reg++) {
            const int di = dib + reg;
            const int colbase = 63 - di;
            #pragma unroll
            for (int nt = 0; nt < 4; nt++) {
                const int dj = nt * 16 + c16;
                float s = (ac[nt][reg] +
                           __bfloat162float(BDs[di][colbase + dj])) * SCALE_F;
                if (j0 + dj > i0 + di + MEMLEN) s = -1e30f;
                sv[nt][reg] = s;
            }
        }
        #pragma unroll
        for (int reg = 0; reg < 4; reg++) {
            float tm = fmaxf(fmaxf(sv[0][reg], sv[1][reg]),
                             fmaxf(sv[2][reg], sv[3][reg]));
            #pragma unroll
            for (int mk = 1; mk < 16; mk <<= 1)
                tm = fmaxf(tm, __shfl_xor(tm, mk));
            const float nm = fmaxf(mrow[reg], tm);
            const float alpha = __expf(mrow[reg] - nm);
            float ev[4];
            #pragma unroll
            for (int nt = 0; nt < 4; nt++) ev[nt] = __expf(sv[nt][reg] - nm);
            float ps = ev[0] + ev[1] + ev[2] + ev[3];
            #pragma unroll
            for (int mk = 1; mk < 16; mk <<= 1)
                ps += __shfl_xor(ps, mk);
            lrow[reg] = lrow[reg] * alpha + ps;
            mrow[reg] = nm;
            #pragma unroll
            for (int nt = 0; nt < 4; nt++) {
                Oacc[nt][reg] *= alpha;
                BDs[dib + reg][nt * 16 + c16] = __float2bfloat16(ev[nt]);
            }
        }
        // ---- PV: P intra-wave stripe, Vt covered by phase-1 barrier ----
        short8 p0 = *(const short8*)&BDs[wave * 16 + c16][g * 8];
        short8 p1 = *(const short8*)&BDs[wave * 16 + c16][32 + g * 8];
        #pragma unroll
        for (int nt = 0; nt < 4; nt++) {
            Oacc[nt] = __builtin_amdgcn_mfma_f32_16x16x32_bf16(
                           p0, *(const short8*)&Vt[nt * 16 + c16][g * 8], Oacc[nt], 0, 0, 0);
            Oacc[nt] = __builtin_amdgcn_mfma_f32_16x16x32_bf16(
                           p1, *(const short8*)&Vt[nt * 16 + c16][32 + g * 8], Oacc[nt], 0, 0, 0);
        }
        __syncthreads();                           // protect K/R/V from next staging
    }

    float invl[4];
    #pragma unroll
    for (int reg = 0; reg < 4; reg++) invl[reg] = 1.f / lrow[reg];
    #pragma unroll
    for (int nt = 0; nt < 4; nt++)
        #pragma unroll
        for (int reg = 0; reg < 4; reg++)
            vec[((size_t)(i0 + dib + reg) * NBAT + b) * HDIM + h * DHEAD + nt * 16 + c16]
                = __float2bfloat16(Oacc[nt][reg] * invl[reg]);
    if (c16 == 0) {
        #pragma unroll
        for (int reg = 0; reg < 4; reg++) {
            const int idx = ((i0 + dib + reg) * NBAT + b) * NHEAD + h;
            m_arr[idx] = mrow[reg];
            l_arr[idx] = lrow[reg];
        }
    }
}

// ============ attn matrix via MFMA — balanced flattened grid + bh-split ============
__global__ __launch_bounds__(256)
void attn_mat4_k(const float* __restrict__ q, const bf16* __restrict__ kv,
                 const bf16* __restrict__ rg, const float* __restrict__ ub,
                 const float* __restrict__ vb, const float* __restrict__ m_arr,
                 const float* __restrict__ l_arr, float* __restrict__ attn)
{
    int f = blockIdx.x, it = 0, base = 0;
    for (it = 0; it < 16; it++) {
        const int cnt = it + 17;
        if (f < base + cnt) break;
        base += cnt;
    }
    const int i0 = it * 64;
    const int j0 = (f - base) * 64;
    const int bhb = blockIdx.y * 16;

    __shared__ alignas(16) bf16 Ks[64][72];
    __shared__ alignas(16) bf16 Rs[128][72];
    __shared__ alignas(16) bf16 BDs[64][136];
    const int tid = threadIdx.x;
    const int wave = tid >> 6, lane = tid & 63;
    const int g = lane >> 4, c16 = lane & 15;
    const int dib = wave * 16 + g * 4;
    const int jj0 = j0 + (LQ - 64) - i0;
    float psum[4][4] = {};

    for (int bh = bhb; bh < bhb + 16; bh++) {
        const int b = bh >> 4, h = bh & 15;
        Frag8 fu0, fu1, fv0, fv1;
        {
            const float* qrow = q + ((size_t)(i0 + wave * 16 + c16) * NBAT + b) * HDIM + h * DHEAD;
            const float* ubp = ub + h * DHEAD;
            const float* vbp = vb + h * DHEAD;
            #pragma unroll
            for (int e = 0; e < 8; e++) {
                float q0 = qrow[g * 8 + e], q1 = qrow[32 + g * 8 + e];
                fu0.h[e] = __float2bfloat16(q0 + ubp[g * 8 + e]);
                fu1.h[e] = __float2bfloat16(q1 + ubp[32 + g * 8 + e]);
                fv0.h[e] = __float2bfloat16(q0 + vbp[g * 8 + e]);
                fv1.h[e] = __float2bfloat16(q1 + vbp[32 + g * 8 + e]);
            }
        }
        {
            const int row = tid >> 2, dbase = (tid & 3) * 16;
            const bf16* src = kv + ((size_t)(j0 + row) * NBAT + b) * (2 * HDIM)
                                 + h * DHEAD + dbase;
            *(uint4*)&Ks[row][dbase]     = *(const uint4*)src;
            *(uint4*)&Ks[row][dbase + 8] = *(const uint4*)(src + 8);
        }
        {
            const int row = tid >> 1, dbase = (tid & 1) * 32;
            const int jj = jj0 + row;
            if (jj < TKEY) {
                const bf16* src = rg + ((size_t)jj * NBAT + b) * HDIM + h * DHEAD + dbase;
                #pragma unroll
                for (int u = 0; u < 4; u++)
                    *(uint4*)&Rs[row][dbase + u * 8] = *(const uint4*)(src + u * 8);
            } else {
                const uint4 z = make_uint4(0, 0, 0, 0);
                #pragma unroll
                for (int u = 0; u < 4; u++)
                    *(uint4*)&Rs[row][dbase + u * 8] = z;
            }
        }
        __syncthreads();
        f32x4 ac[4];
        #pragma unroll
        for (int nt = 0; nt < 4; nt++) {
            ac[nt] = (f32x4)(0.f);
            ac[nt] = __builtin_amdgcn_mfma_f32_16x16x32_bf16(
                         fu0.v, *(const short8*)&Ks[nt * 16 + c16][g * 8], ac[nt], 0, 0, 0);
            ac[nt] = __builtin_amdgcn_mfma_f32_16x16x32_bf16(
                         fu1.v, *(const short8*)&Ks[nt * 16 + c16][32 + g * 8], ac[nt], 0, 0, 0);
        }
        #pragma unroll
        for (int nt = 0; nt < 8; nt++) {
            f32x4 bd = (f32x4)(0.f);
            bd = __builtin_amdgcn_mfma_f32_16x16x32_bf16(
                     fv0.v, *(const short8*)&Rs[nt * 16 + c16][g * 8], bd, 0, 0, 0);
            bd = __builtin_amdgcn_mfma_f32_16x16x32_bf16(
                     fv1.v, *(const short8*)&Rs[nt * 16 + c16][32 + g * 8], bd, 0, 0, 0);
            #pragma unroll
            for (int reg = 0; reg < 4; reg++)
                BDs[dib + reg][nt * 16 + c16] = __float2bfloat16(bd[reg]);
        }
        #pragma unroll
        for (int reg = 0; reg < 4; reg++) {
            const int di = dib + reg;
            const int colbase = 63 - di;
            const int idx = ((i0 + di) * NBAT + b) * NHEAD + h;
            const float mi = m_arr[idx];
            const float il = 1.f / l_arr[idx];
            #pragma unroll
            for (int nt = 0; nt < 4; nt++) {
                const int dj = nt * 16 + c16;
                float s = (ac[nt][reg] +
                           __bfloat162float(BDs[di][colbase + dj])) * SCALE_F;
                float p = (j0 + dj > i0 + di + MEMLEN) ? 0.f : __expf(s - mi) * il;
                psum[nt][reg] += p;
            }
        }
        __syncthreads();
    }
    const float inv = 1.f / (NBAT * NHEAD);
    #pragma unroll
    for (int nt = 0; nt < 4; nt++)
        #pragma unroll
        for (int reg = 0; reg < 4; reg++)
            atomicAdd(&attn[(size_t)(i0 + dib + reg) * TKEY + j0 + nt * 16 + c16],
                      psum[nt][reg] * inv);
}

// ---------------- fused residual + LayerNorm ----------------
template<typename T1, typename T2, typename TOUT>
__global__ __launch_bounds__(256)
void ln_k(const T1* __restrict__ a, const T2* __restrict__ c,
          const float* __restrict__ g, const float* __restrict__ bb,
          TOUT* __restrict__ out)
{
    const int row = blockIdx.x;
    const int tid = threadIdx.x;
    const size_t base = (size_t)row * DMOD;
    float vals[4];
    float s = 0.f, sq = 0.f;
    #pragma unroll
    for (int t = 0; t < 4; t++) {
        const int dcol = tid + t * 256;
        float v = ldf(a + base + dcol) + ldf(c + base + dcol);
        vals[t] = v; s += v; sq += v * v;
    }
    __shared__ float rs[256], rq[256];
    rs[tid] = s; rq[tid] = sq;
    __syncthreads();
    for (int st = 128; st > 0; st >>= 1) {
        if (tid < st) { rs[tid] += rs[tid + st]; rq[tid] += rq[tid + st]; }
        __syncthreads();
    }
    const float mean = rs[0] / DMOD;
    const float var = rq[0] / DMOD - mean * mean;
    const float rstd = rsqrtf(fmaxf(var, 0.f) + EPS_F);
    #pragma unroll
    for (int t = 0; t < 4; t++) {
        const int dcol = tid + t * 256;
        float v = (vals[t] - mean) * rstd * g[dcol] + bb[dcol];
        stf(out + base + dcol, v);
    }
}

// ---------------- residual + NP split-K fp32 partials (+optional bias) + LayerNorm ----
template<typename TA, int NP, bool HASB, typename TOUT>
__global__ __launch_bounds__(256)
void lnp_k(const TA* __restrict__ a, const float* __restrict__ part, size_t pstride,
           const float* __restrict__ biasvec, const float* __restrict__ g,
           const float* __restrict__ bb, TOUT* __restrict__ out)
{
    const int row = blockIdx.x;
    const int tid = threadIdx.x;
    const size_t base = (size_t)row * DMOD;
    float vals[4];
    float s = 0.f, sq = 0.f;
    #pragma unroll
    for (int t = 0; t < 4; t++) {
        const int dcol = tid + t * 256;
        float v = ldf(a + base + dcol);
        #pragma unroll
        for (int p = 0; p < NP; p++) v += part[(size_t)p * pstride + base + dcol];
        if (HASB) v += biasvec[dcol];
        vals[t] = v; s += v; sq += v * v;
    }
    __shared__ float rs[256], rq[256];
    rs[tid] = s; rq[tid] = sq;
    __syncthreads();
    for (int st = 128; st > 0; st >>= 1) {
        if (tid < st) { rs[tid] += rs[tid + st]; rq[tid] += rq[tid + st]; }
        __syncthreads();
    }
    const float mean = rs[0] / DMOD;
    const float var = rq[0] / DMOD - mean * mean;
    const float rstd = rsqrtf(fmaxf(var, 0.f) + EPS_F);
    #pragma unroll
    for (int t = 0; t < 4; t++) {
        const int dcol = tid + t * 256;
        float v = (vals[t] - mean) * rstd * g[dcol] + bb[dcol];
        stf(out + base + dcol, v);
    }
}

__global__ void fill_zero_k(float* __restrict__ p, int n) {
    int i = blockIdx.x * 256 + threadIdx.x;
    if (i < n) p[i] = 0.f;
}

extern "C" void kernel_launch(void* const* d_in, const int* in_sizes, int n_in,
                              void* d_out, int out_size, void* d_ws, size_t ws_size,
                              hipStream_t stream)
{
    const float* x    = (const float*)d_in[0];
    const float* pos  = (const float*)d_in[1];
    const float* ub   = (const float*)d_in[2];
    const float* vb   = (const float*)d_in[3];
    const float* memp = (const float*)d_in[4];
    const float* Wq   = (const float*)d_in[5];
    const float* Wkv  = (const float*)d_in[6];
    const float* Wo   = (const float*)d_in[7];
    const float* Wrel = (const float*)d_in[8];
    const float* ln1g = (const float*)d_in[9];
    const float* ln1b = (const float*)d_in[10];
    const float* W1   = (const float*)d_in[11];
    const float* b1   = (const float*)d_in[12];
    const float* W2   = (const float*)d_in[13];
    const float* b2   = (const float*)d_in[14];
    const float* ln2g = (const float*)d_in[15];
    const float* ln2b = (const float*)d_in[16];

    // ---- workspace, lifetime-aliased ----
    char* wsb = (char*)d_ws;
    const size_t MB = 1048576;
    bf16*  kvb   = (bf16*)(wsb + 0);
    bf16*  h1    = (bf16*)(wsb + 0);
    bf16*  rb    = (bf16*)(wsb + 16 * MB);
    bf16*  aout  = (bf16*)(wsb + 16 * MB);
    bf16*  f2o   = (bf16*)(wsb + 16 * MB);
    bf16*  out1  = (bf16*)(wsb + 20 * MB);
    bf16*  vecb  = (bf16*)(wsb + 24 * MB);
    float* m_arr = (float*)(wsb + 28 * MB);
    float* l_arr = (float*)(wsb + 28 * MB + 131072);
    const size_t ws_need_old = 28 * MB + 262144;
    bf16*  catc  = (bf16*)(wsb + 30 * MB);
    bf16*  posc  = (bf16*)(wsb + 38 * MB);
    float* part2 = (float*)(wsb + 30 * MB);
    bf16*  wscr  = (bf16*)(wsb + 46 * MB);
    const size_t ws_need_new = 54 * MB;

    float* outp  = (float*)d_out;
    float* attnp = outp + (size_t)LQ * NBAT * DMOD;
    float* qb    = outp;

    const dim3 blk(256);
    const size_t PSTRIDE = (size_t)LQ * NBAT * DMOD;
    const int NATTN = LQ * TKEY;

    if (ws_size < ws_need_old) {
        fill_zero_k<<<dim3((out_size + 255) / 256), blk, 0, stream>>>(outp, out_size);
        return;
    }

    if (ws_size >= ws_need_new) {
        // ======== fast path ========
        const int nCat = MEMLEN * NBAT * DMOD;
        const int nPos = TKEY * NBAT * DMOD;
        cvt3_bf16_k<<<dim3((2 * nCat + nPos) / 2048), blk, 0, stream>>>(
            memp, catc, nCat, x, catc + (size_t)nCat, nCat, pos, posc, nPos);
        tcvt3_k<<<dim3(1024), blk, 0, stream>>>(
            Wkv, wscr, Wrel, wscr + (size_t)2 * MB, Wq, wscr + (size_t)3 * MB);

        mgemm128_k<1, false, bf16><<<dim3(2 * HDIM / 128, TKEY * NBAT / 128, 1), blk, 0, stream>>>(
            catc, wscr, nullptr, kvb, TKEY * NBAT, 2 * HDIM, DMOD);
        mgemm128_k<1, false, bf16><<<dim3(HDIM / 128, TKEY * NBAT / 128, 1), blk, 0, stream>>>(
            posc, wscr + (size_t)2 * MB, nullptr, rb, TKEY * NBAT, HDIM, DMOD);
        mgemm128_k<1, false, float><<<dim3(HDIM / 128, LQ * NBAT / 128, 1), blk, 0, stream>>>(
            catc + (size_t)nCat, wscr + (size_t)3 * MB, nullptr, qb, LQ * NBAT, HDIM, DMOD);

        fill_zero_k<<<dim3((NATTN + 255) / 256), blk, 0, stream>>>(attnp, NATTN);

        flash_attn_k<<<dim3(LQ / 64, NBAT * NHEAD), blk, 0, stream>>>(
            qb, kvb, rb, ub, vb, m_arr, l_arr, vecb);
        attn_mat4_k<<<dim3(392, 2), blk, 0, stream>>>(
            qb, kvb, rb, ub, vb, m_arr, l_arr, attnp);

        tcvt_bf16_k<<<dim3(DMOD / 64, HDIM / 64), blk, 0, stream>>>(Wo, wscr, HDIM, DMOD);
        mgemm128_k<2, false, float><<<dim3(DMOD / 128, LQ * NBAT / 128, 2), blk, 0, stream>>>(
            vecb, wscr, nullptr, part2, LQ * NBAT, DMOD, HDIM);
        lnp_k<float, 2, false, bf16><<<dim3(LQ * NBAT), blk, 0, stream>>>(
            x, part2, PSTRIDE, nullptr, ln1g, ln1b, out1);
        tcvt_bf16_k<<<dim3(DFFN / 64, DMOD / 64), blk, 0, stream>>>(W1, wscr, DMOD, DFFN);
        mgemm128_k<1, true, bf16><<<dim3(DFFN / 128, LQ * NBAT / 128, 1), blk, 0, stream>>>(
            out1, wscr, b1, h1, LQ * NBAT, DFFN, DMOD);
        tcvt_bf16_k<<<dim3(DMOD / 64, DFFN / 64), blk, 0, stream>>>(W2, wscr, DFFN, DMOD);
        mgemm128_k<2, false, float><<<dim3(DMOD / 128, LQ * NBAT / 128, 2), blk, 0, stream>>>(
            h1, wscr, nullptr, part2, LQ * NBAT, DMOD, DFFN);
        lnp_k<bf16, 2, true, float><<<dim3(LQ * NBAT), blk, 0, stream>>>(
            out1, part2, PSTRIDE, b2, ln2g, ln2b, outp);
        return;
    }

    // ======== fallback path ========
    mgemm64_k<float, bf16, false><<<dim3(2 * HDIM / 64, TKEY * NBAT / 64), blk, 0, stream>>>(
        memp, x, MEMLEN * NBAT, Wkv, nullptr, kvb, TKEY * NBAT, 2 * HDIM, DMOD);
    mgemm64_k<float, bf16, false><<<dim3(HDIM / 64, TKEY * NBAT / 64), blk, 0, stream>>>(
        pos, pos, TKEY * NBAT, Wrel, nullptr, rb, TKEY * NBAT, HDIM, DMOD);
    mgemm64_k<float, float, false><<<dim3(HDIM / 64, LQ * NBAT / 64), blk, 0, stream>>>(
        x, x, LQ * NBAT, Wq, nullptr, qb, LQ * NBAT, HDIM, DMOD);

    fill_zero_k<<<dim3((NATTN + 255) / 256), blk, 0, stream>>>(attnp, NATTN);
    flash_attn_k<<<dim3(LQ / 64, NBAT * NHEAD), blk, 0, stream>>>(
        qb, kvb, rb, ub, vb, m_arr, l_arr, vecb);
    attn_mat4_k<<<dim3(392, 2), blk, 0, stream>>>(
        qb, kvb, rb, ub, vb, m_arr, l_arr, attnp);

    mgemm64_k<bf16, bf16, false><<<dim3(DMOD / 64, LQ * NBAT / 64), blk, 0, stream>>>(
        vecb, vecb, LQ * NBAT, Wo, nullptr, aout, LQ * NBAT, DMOD, HDIM);
    ln_k<float, bf16, bf16><<<dim3(LQ * NBAT), blk, 0, stream>>>(x, aout, ln1g, ln1b, out1);
    mgemm64_k<bf16, bf16, true><<<dim3(DFFN / 64, LQ * NBAT / 64), blk, 0, stream>>>(
        out1, out1, LQ * NBAT, W1, b1, h1, LQ * NBAT, DFFN, DMOD);
    mgemm64_k<bf16, bf16, false><<<dim3(DMOD / 64, LQ * NBAT / 64), blk, 0, stream>>>(
        h1, h1, LQ * NBAT, W2, b2, f2o, LQ * NBAT, DMOD, DFFN);
    ln_k<bf16, bf16, float><<<dim3(LQ * NBAT), blk, 0, stream>>>(out1, f2o, ln2g, ln2b, outp);
}